// Round 2
// baseline (317.287 us; speedup 1.0000x reference)
//
#include <hip/hip_runtime.h>
#include <hip/hip_bf16.h>

// DeformableTemporalAttention — MI355X
// B=4, N=4096 (64x64), T=3, D=256, H=8, P=9, dh=32
//
// Math notes:
//  - einsum sums over t with t-independent weights and t-independent grid,
//    and bilinear sampling is linear => sample from sum_t(val_t).
//  - sum_t val_t = (sum_t x_t) @ W_v, fused into the V-GEMM A-tile load.
//
// Pipeline:
//  1. gemm<0>: valsum[b,h,n,d] = (sum_t x[b,n,t,:]) @ W_v + 3*b_v
//  2. gemm<1>: proj[b*n][216]  = x[b,n,1,:] @ [W_off | W_attn] + [b_off|b_attn]
//  3. sampler: per (b,n): softmax+loc prep (LDS), 9 pts x 4 corners
//  4. gemm<2>: out = inter @ W_o + b_o

#define HW_ 64
#define NN_ 4096
#define TT_ 3
#define DD_ 256
#define NH_ 8
#define NP_ 9
#define DH_ 32
#define BB_ 4

// ---------------- GEMM ----------------
// C[M x NC] = A[M x 256] @ W[256 x NC] + bias
// MODE 0: A-row = sum_t x[row, t, :], W=W_v (256 cols), out=valsum (B,H,N,32), bias*3
// MODE 1: A-row = x[row, 1, :], W=[W_off(144)|W_attn(72)], out=proj[row][216]
// MODE 2: A-row = inter[row], W=W_o, out=out[row][256]
template <int MODE>
__global__ __launch_bounds__(256) void gemm_k(const float* __restrict__ A,
                                              const float* __restrict__ W0,
                                              const float* __restrict__ W1,
                                              const float* __restrict__ bias0,
                                              const float* __restrict__ bias1,
                                              float* __restrict__ Cout) {
  constexpr int BM = 128, BN = 64, BK = 64;
  __shared__ float Alds[BK][BM + 4];   // transposed: [k][m]
  __shared__ float Blds[BK][BN + 4];

  const int m0 = blockIdx.x * BM;
  const int n0 = blockIdx.y * BN;
  const int tid = threadIdx.x;
  const int tn = tid & 15;        // 0..15 -> 4 cols each
  const int tm = tid >> 4;        // 0..15 -> 8 rows each

  float acc[8][4];
#pragma unroll
  for (int i = 0; i < 8; ++i)
#pragma unroll
    for (int j = 0; j < 4; ++j) acc[i][j] = 0.f;

  for (int k0 = 0; k0 < DD_; k0 += BK) {
    // ---- load A tile (128 rows x 64 k), 8 float4 per thread, transpose into LDS
#pragma unroll
    for (int i = 0; i < 8; ++i) {
      int id = i * 256 + tid;
      int arow = id >> 4;          // 0..127
      int kq = id & 15;            // float4 index within BK
      int grow = m0 + arow;        // global row = b*4096+n
      float4 v;
      if (MODE == 0) {
        const float* base = A + ((size_t)grow * TT_) * DD_ + (k0 + kq * 4);
        float4 a0 = *(const float4*)(base);
        float4 a1 = *(const float4*)(base + DD_);
        float4 a2 = *(const float4*)(base + 2 * DD_);
        v = make_float4(a0.x + a1.x + a2.x, a0.y + a1.y + a2.y,
                        a0.z + a1.z + a2.z, a0.w + a1.w + a2.w);
      } else if (MODE == 1) {
        v = *(const float4*)(A + ((size_t)grow * TT_ + 1) * DD_ + (k0 + kq * 4));
      } else {
        v = *(const float4*)(A + (size_t)grow * DD_ + (k0 + kq * 4));
      }
      int kk = kq * 4;
      Alds[kk + 0][arow] = v.x;
      Alds[kk + 1][arow] = v.y;
      Alds[kk + 2][arow] = v.z;
      Alds[kk + 3][arow] = v.w;
    }
    // ---- load B tile (64 k x 64 n), 4 float4 per thread
#pragma unroll
    for (int i = 0; i < 4; ++i) {
      int id = i * 256 + tid;
      int kk = id >> 4;            // 0..63
      int nq = id & 15;
      int gn = n0 + nq * 4;
      float4 v;
      if (MODE == 1) {
        if (gn < 144)
          v = *(const float4*)(W0 + (size_t)(k0 + kk) * 144 + gn);
        else if (gn < 216)
          v = *(const float4*)(W1 + (size_t)(k0 + kk) * 72 + (gn - 144));
        else
          v = make_float4(0.f, 0.f, 0.f, 0.f);
      } else {
        v = *(const float4*)(W0 + (size_t)(k0 + kk) * DD_ + gn);
      }
      *(float4*)&Blds[kk][nq * 4] = v;
    }
    __syncthreads();

#pragma unroll 8
    for (int k = 0; k < BK; ++k) {
      float a[8], b[4];
      *(float4*)&a[0] = *(const float4*)&Alds[k][tm * 8];
      *(float4*)&a[4] = *(const float4*)&Alds[k][tm * 8 + 4];
      *(float4*)&b[0] = *(const float4*)&Blds[k][tn * 4];
#pragma unroll
      for (int i = 0; i < 8; ++i)
#pragma unroll
        for (int j = 0; j < 4; ++j) acc[i][j] += a[i] * b[j];
    }
    __syncthreads();
  }

  // ---- epilogue
  const int c0 = n0 + tn * 4;
  if (MODE == 1 && c0 >= 216) return;

  float4 bv;
  if (MODE == 1) {
    if (c0 < 144)
      bv = *(const float4*)(bias0 + c0);
    else
      bv = *(const float4*)(bias1 + (c0 - 144));
  } else {
    bv = *(const float4*)(bias0 + c0);
    if (MODE == 0) {  // bias summed over T
      bv.x *= 3.f; bv.y *= 3.f; bv.z *= 3.f; bv.w *= 3.f;
    }
  }

#pragma unroll
  for (int i = 0; i < 8; ++i) {
    int grow = m0 + tm * 8 + i;
    float4 r = make_float4(acc[i][0] + bv.x, acc[i][1] + bv.y,
                           acc[i][2] + bv.z, acc[i][3] + bv.w);
    if (MODE == 0) {
      int b = grow >> 12, n = grow & 4095;
      int h = c0 >> 5, d0 = c0 & 31;
      *(float4*)(Cout + (((size_t)(b * NH_ + h) * NN_ + n) * DH_ + d0)) = r;
    } else if (MODE == 1) {
      *(float4*)(Cout + (size_t)grow * 216 + c0) = r;
    } else {
      *(float4*)(Cout + (size_t)grow * DD_ + c0) = r;
    }
  }
}

// ---------------- Sampler ----------------
// block = one (b,n); 256 threads = (h, d)
__global__ __launch_bounds__(256) void sample_k(const float* __restrict__ valsum,
                                                const float* __restrict__ proj,
                                                float* __restrict__ inter) {
  const int row = blockIdx.x;            // b*4096 + n
  const int b = row >> 12, n = row & 4095;
  __shared__ float sgx[NH_][NP_], sgy[NH_][NP_], sa[NH_][NP_];

  const int tid = threadIdx.x;
  if (tid < NH_) {
    const int h = tid;
    const float* pr = proj + (size_t)row * 216;
    const float refx = (float)(n & 63) * (2.0f / 63.0f) - 1.0f;
    const float refy = (float)(n >> 6) * (2.0f / 63.0f) - 1.0f;
    float lg[NP_];
    float mx = -1e30f;
#pragma unroll
    for (int p = 0; p < NP_; ++p) {
      lg[p] = pr[144 + h * NP_ + p];
      mx = fmaxf(mx, lg[p]);
    }
    float s = 0.f;
#pragma unroll
    for (int p = 0; p < NP_; ++p) {
      lg[p] = __expf(lg[p] - mx);
      s += lg[p];
    }
    const float inv = 1.0f / s;
#pragma unroll
    for (int p = 0; p < NP_; ++p) {
      float ox = pr[(h * NP_ + p) * 2 + 0];
      float oy = pr[(h * NP_ + p) * 2 + 1];
      sgx[h][p] = (refx + ox + 1.0f) * 0.5f * 63.0f;
      sgy[h][p] = (refy + oy + 1.0f) * 0.5f * 63.0f;
      sa[h][p] = lg[p] * inv;
    }
  }
  __syncthreads();

  const int h = tid >> 5, d = tid & 31;
  const float* vb = valsum + ((size_t)(b * NH_ + h) * NN_) * DH_ + d;
  float acc = 0.f;
#pragma unroll
  for (int p = 0; p < NP_; ++p) {
    const float gx = sgx[h][p], gy = sgy[h][p], a = sa[h][p];
    const float fx0 = floorf(gx), fy0 = floorf(gy);
    const float wx1 = gx - fx0, wy1 = gy - fy0;
    const float wx0 = 1.f - wx1, wy0 = 1.f - wy1;
    const int x0 = (int)fx0, y0 = (int)fy0;
    const int x1 = x0 + 1, y1 = y0 + 1;
    const bool vx0 = (x0 >= 0) & (x0 < HW_), vx1 = (x1 >= 0) & (x1 < HW_);
    const bool vy0 = (y0 >= 0) & (y0 < HW_), vy1 = (y1 >= 0) & (y1 < HW_);
    const int x0c = min(max(x0, 0), HW_ - 1), x1c = min(max(x1, 0), HW_ - 1);
    const int y0c = min(max(y0, 0), HW_ - 1), y1c = min(max(y1, 0), HW_ - 1);
    if (vx0 & vy0) acc += (wx0 * wy0 * a) * vb[(size_t)(y0c * HW_ + x0c) * DH_];
    if (vx1 & vy0) acc += (wx1 * wy0 * a) * vb[(size_t)(y0c * HW_ + x1c) * DH_];
    if (vx0 & vy1) acc += (wx0 * wy1 * a) * vb[(size_t)(y1c * HW_ + x0c) * DH_];
    if (vx1 & vy1) acc += (wx1 * wy1 * a) * vb[(size_t)(y1c * HW_ + x1c) * DH_];
  }
  inter[(size_t)row * DD_ + tid] = acc;
}

extern "C" void kernel_launch(void* const* d_in, const int* in_sizes, int n_in,
                              void* d_out, int out_size, void* d_ws, size_t ws_size,
                              hipStream_t stream) {
  const float* x      = (const float*)d_in[0];
  const float* W_off  = (const float*)d_in[1];
  const float* b_off  = (const float*)d_in[2];
  const float* W_attn = (const float*)d_in[3];
  const float* b_attn = (const float*)d_in[4];
  const float* W_v    = (const float*)d_in[5];
  const float* b_v    = (const float*)d_in[6];
  const float* W_o    = (const float*)d_in[7];
  const float* b_o    = (const float*)d_in[8];
  float* out = (float*)d_out;

  const int M = BB_ * NN_;  // 16384
  float* ws = (float*)d_ws;
  float* valsum = ws;                               // 16384*256
  float* proj = valsum + (size_t)M * DD_;           // 16384*216
  float* inter = proj + (size_t)M * 216;            // 16384*256

  dim3 blk(256);
  // 1. valsum = (sum_t x) @ W_v + 3*b_v  -> (B,H,N,32)
  gemm_k<0><<<dim3(M / 128, DD_ / 64), blk, 0, stream>>>(x, W_v, nullptr, b_v, nullptr, valsum);
  // 2. proj = x[:,:,1,:] @ [W_off|W_attn] + bias -> (M,216)
  gemm_k<1><<<dim3(M / 128, 4), blk, 0, stream>>>(x, W_off, W_attn, b_off, b_attn, proj);
  // 3. sample + attention-combine -> inter (M,256)
  sample_k<<<dim3(M), blk, 0, stream>>>(valsum, proj, inter);
  // 4. out = inter @ W_o + b_o
  gemm_k<2><<<dim3(M / 128, DD_ / 64), blk, 0, stream>>>(inter, W_o, nullptr, b_o, nullptr, out);
}

// Round 3
// 191.706 us; speedup vs baseline: 1.6551x; 1.6551x over previous
//
#include <hip/hip_runtime.h>
#include <hip/hip_bf16.h>

// DeformableTemporalAttention — MI355X (gfx950)
// B=4, N=4096 (64x64), T=3, D=256, H=8, P=9, dh=32
//
// Pipeline (6 dispatches):
//  1. prep_w : transpose+split weights to bf16 hi/lo [n][k]; pack bcat
//  2. prep_a : asum = sum_t x  -> bf16 hi/lo [M][256]
//  3. mgemm<0>: valsum = asum @ W_v + 3*b_v        (MFMA, 3-pass bf16 split)
//  4. mgemm<1>: proj = x[:,:,1,:] @ [W_off|W_attn] + bcat
//  5. sample_k: bilinear gather + attn combine -> inter (bf16 hi/lo)
//  6. mgemm<2>: out = inter @ W_o + b_o
//
// t-sum is pulled through the (linear) bilinear sampler: sample(sum_t val_t).

#define NN_ 4096
#define DD_ 256
#define NH_ 8
#define NP_ 9
#define DH_ 32
#define MM_ 16384   // B*N

typedef __attribute__((ext_vector_type(8))) short bf16x8;
typedef __attribute__((ext_vector_type(4))) short bf16x4;
typedef __attribute__((ext_vector_type(4))) float f32x4;

static __device__ __forceinline__ unsigned short f2bf(float f) {
  unsigned int u = __float_as_uint(f);
  u = (u + 0x7fff + ((u >> 16) & 1)) >> 16;   // RN-even
  return (unsigned short)u;
}
static __device__ __forceinline__ float bf2f(unsigned short h) {
  return __uint_as_float(((unsigned int)h) << 16);
}

// ---------------- prep_w: weights -> transposed bf16 hi/lo ----------------
// grid 256 blocks x 256 thr; block = n (output row), thread = k
__global__ __launch_bounds__(256) void prep_w(
    const float* __restrict__ W_off, const float* __restrict__ W_attn,
    const float* __restrict__ W_v, const float* __restrict__ W_o,
    const float* __restrict__ b_off, const float* __restrict__ b_attn,
    unsigned short* __restrict__ wvh, unsigned short* __restrict__ wvl,
    unsigned short* __restrict__ wch, unsigned short* __restrict__ wcl,
    unsigned short* __restrict__ woh, unsigned short* __restrict__ wol,
    float* __restrict__ bcat) {
  const int n = blockIdx.x, t = threadIdx.x;
  {
    float v = W_v[(size_t)t * 256 + n];
    unsigned short h = f2bf(v);
    wvh[n * 256 + t] = h; wvl[n * 256 + t] = f2bf(v - bf2f(h));
  }
  {
    float v = W_o[(size_t)t * 256 + n];
    unsigned short h = f2bf(v);
    woh[n * 256 + t] = h; wol[n * 256 + t] = f2bf(v - bf2f(h));
  }
  if (n < 216) {
    float v = (n < 144) ? W_off[(size_t)t * 144 + n] : W_attn[(size_t)t * 72 + (n - 144)];
    unsigned short h = f2bf(v);
    wch[n * 256 + t] = h; wcl[n * 256 + t] = f2bf(v - bf2f(h));
  }
  if (n == 0 && t < 216) bcat[t] = (t < 144) ? b_off[t] : b_attn[t - 144];
}

// ---------------- prep_a: asum = sum_t x -> bf16 hi/lo [M][256] -----------
__global__ __launch_bounds__(256) void prep_a(const float* __restrict__ x,
                                              unsigned short* __restrict__ ash,
                                              unsigned short* __restrict__ asl) {
  const int gid = blockIdx.x * 256 + threadIdx.x;   // 0 .. M*64-1
  const int row = gid >> 6, c4 = (gid & 63) * 4;
  const float* xr = x + (size_t)row * 768 + c4;
  float4 a0 = *(const float4*)xr;
  float4 a1 = *(const float4*)(xr + 256);
  float4 a2 = *(const float4*)(xr + 512);
  float s[4] = {a0.x + a1.x + a2.x, a0.y + a1.y + a2.y,
                a0.z + a1.z + a2.z, a0.w + a1.w + a2.w};
  bf16x4 hv, lv;
#pragma unroll
  for (int j = 0; j < 4; ++j) {
    unsigned short h = f2bf(s[j]);
    hv[j] = (short)h;
    lv[j] = (short)f2bf(s[j] - bf2f(h));
  }
  *(bf16x4*)(ash + (size_t)row * 256 + c4) = hv;
  *(bf16x4*)(asl + (size_t)row * 256 + c4) = lv;
}

// ---------------- mgemm: C[Mx NC] = A @ Bt^T + bias (3-pass bf16 split) ----
// A: bf16 hi/lo [M][256]  (MODE1: fp32 x mid-slice, converted in staging)
// Bt: bf16 hi/lo [NC][256] (n-major, i.e. W transposed)
// MODE 0: NC=256, out valsum (B,H,N,32) f32, bias*3
// MODE 1: NC=216, out proj [M][216] f32
// MODE 2: NC=256, out [M][256] f32
template <int MODE>
__global__ __launch_bounds__(256) void mgemm(const unsigned short* __restrict__ Ahi,
                                             const unsigned short* __restrict__ Alo,
                                             const float* __restrict__ X,
                                             const unsigned short* __restrict__ Bth,
                                             const unsigned short* __restrict__ Btl,
                                             const float* __restrict__ bias,
                                             float* __restrict__ Cout) {
  constexpr int NC = (MODE == 1) ? 216 : 256;
  __shared__ unsigned short Ah[128][64], Al[128][64], Bh[128][64], Bl[128][64];
  const int m0 = blockIdx.x * 128, n0 = blockIdx.y * 128;
  const int tid = threadIdx.x;
  const int wid = tid >> 6, lane = tid & 63;
  const int am = (wid >> 1) * 64, bn = (wid & 1) * 64;
  const int fr = lane & 15, kg = lane >> 4;

  f32x4 acc[4][4];
#pragma unroll
  for (int i = 0; i < 4; ++i)
#pragma unroll
    for (int j = 0; j < 4; ++j) acc[i][j] = (f32x4)(0.f);

  for (int k0 = 0; k0 < 256; k0 += 64) {
    // ---- stage A (128 x 64) hi/lo
#pragma unroll
    for (int i = 0; i < 4; ++i) {
      int cid = i * 256 + tid;
      int r = cid >> 3, c = cid & 7;
      int dst = r * 64 + ((c ^ (r & 7)) * 8);
      bf16x8 hv, lv;
      if (MODE == 1) {
        const float* src = X + ((size_t)(m0 + r) * 3 + 1) * 256 + k0 + c * 8;
        float4 f0 = *(const float4*)src, f1 = *(const float4*)(src + 4);
        float vv[8] = {f0.x, f0.y, f0.z, f0.w, f1.x, f1.y, f1.z, f1.w};
#pragma unroll
        for (int j = 0; j < 8; ++j) {
          unsigned short h = f2bf(vv[j]);
          hv[j] = (short)h;
          lv[j] = (short)f2bf(vv[j] - bf2f(h));
        }
      } else {
        size_t off = (size_t)(m0 + r) * 256 + k0 + c * 8;
        hv = *(const bf16x8*)(Ahi + off);
        lv = *(const bf16x8*)(Alo + off);
      }
      *(bf16x8*)(&Ah[0][0] + dst) = hv;
      *(bf16x8*)(&Al[0][0] + dst) = lv;
    }
    // ---- stage B (128 n-rows x 64 k) hi/lo
#pragma unroll
    for (int i = 0; i < 4; ++i) {
      int cid = i * 256 + tid;
      int r = cid >> 3, c = cid & 7;
      int dst = r * 64 + ((c ^ (r & 7)) * 8);
      bf16x8 hv = (bf16x8)(short)0, lv = (bf16x8)(short)0;
      int nrow = n0 + r;
      if (NC == 256 || nrow < NC) {
        size_t off = (size_t)nrow * 256 + k0 + c * 8;
        hv = *(const bf16x8*)(Bth + off);
        lv = *(const bf16x8*)(Btl + off);
      }
      *(bf16x8*)(&Bh[0][0] + dst) = hv;
      *(bf16x8*)(&Bl[0][0] + dst) = lv;
    }
    __syncthreads();

#pragma unroll
    for (int ks = 0; ks < 2; ++ks) {
      bf16x8 ah[4], al[4], bh[4], bl[4];
      const int kc = ks * 4 + kg;
#pragma unroll
      for (int mi = 0; mi < 4; ++mi) {
        int m = am + mi * 16 + fr;
        int o = m * 64 + ((kc ^ (m & 7)) * 8);
        ah[mi] = *(const bf16x8*)(&Ah[0][0] + o);
        al[mi] = *(const bf16x8*)(&Al[0][0] + o);
      }
#pragma unroll
      for (int ni = 0; ni < 4; ++ni) {
        int n = bn + ni * 16 + fr;
        int o = n * 64 + ((kc ^ (n & 7)) * 8);
        bh[ni] = *(const bf16x8*)(&Bh[0][0] + o);
        bl[ni] = *(const bf16x8*)(&Bl[0][0] + o);
      }
#pragma unroll
      for (int mi = 0; mi < 4; ++mi)
#pragma unroll
        for (int ni = 0; ni < 4; ++ni) {
          acc[mi][ni] = __builtin_amdgcn_mfma_f32_16x16x32_bf16(ah[mi], bh[ni], acc[mi][ni], 0, 0, 0);
          acc[mi][ni] = __builtin_amdgcn_mfma_f32_16x16x32_bf16(ah[mi], bl[ni], acc[mi][ni], 0, 0, 0);
          acc[mi][ni] = __builtin_amdgcn_mfma_f32_16x16x32_bf16(al[mi], bh[ni], acc[mi][ni], 0, 0, 0);
        }
    }
    __syncthreads();
  }

  // ---- epilogue: C layout col=lane&15, row=(lane>>4)*4+reg
  const int ro = kg * 4;
#pragma unroll
  for (int mi = 0; mi < 4; ++mi)
#pragma unroll
    for (int ni = 0; ni < 4; ++ni) {
      int col = n0 + bn + ni * 16 + fr;
      if (MODE == 1 && col >= 216) continue;
      int rowb = m0 + am + mi * 16 + ro;
      float bv = bias[col] * (MODE == 0 ? 3.f : 1.f);
#pragma unroll
      for (int r = 0; r < 4; ++r) {
        int grow = rowb + r;
        float v = acc[mi][ni][r] + bv;
        if (MODE == 0) {
          int b = grow >> 12, nn = grow & 4095;
          int h = col >> 5, d = col & 31;
          Cout[(((size_t)(b * NH_ + h) << 12) + nn) * DH_ + d] = v;
        } else if (MODE == 1) {
          Cout[(size_t)grow * 216 + col] = v;
        } else {
          Cout[(size_t)grow * 256 + col] = v;
        }
      }
    }
}

// ---------------- sampler ----------------
// block = one (b,n) pixel, 256 thr = (h, d). XCD-chunked block swizzle.
__global__ __launch_bounds__(256) void sample_k(const float* __restrict__ valsum,
                                                const float* __restrict__ proj,
                                                unsigned short* __restrict__ ihi,
                                                unsigned short* __restrict__ ilo) {
  const int bid = blockIdx.x;
  const int row = ((bid & 7) << 11) + (bid >> 3);   // 8 XCD chunks of 2048
  const int b = row >> 12, n = row & 4095;

  __shared__ int cidx[72][4];
  __shared__ float cw[72][4];
  __shared__ float sa[72];

  const int t = threadIdx.x;
  if (t < 72) {
    const float* pr = proj + (size_t)row * 216;
    float ox = pr[t * 2], oy = pr[t * 2 + 1];
    float gx = (float)(n & 63) + ox * 31.5f;
    float gy = (float)(n >> 6) + oy * 31.5f;
    float fx0 = floorf(gx), fy0 = floorf(gy);
    float wx1 = gx - fx0, wy1 = gy - fy0;
    float wx0 = 1.f - wx1, wy0 = 1.f - wy1;
    int x0 = (int)fx0, y0 = (int)fy0, x1 = x0 + 1, y1 = y0 + 1;
    bool vx0 = (x0 >= 0) & (x0 < 64), vx1 = (x1 >= 0) & (x1 < 64);
    bool vy0 = (y0 >= 0) & (y0 < 64), vy1 = (y1 >= 0) & (y1 < 64);
    int x0c = min(max(x0, 0), 63), x1c = min(max(x1, 0), 63);
    int y0c = min(max(y0, 0), 63), y1c = min(max(y1, 0), 63);
    cidx[t][0] = (y0c * 64 + x0c) * DH_; cw[t][0] = (vx0 & vy0) ? wx0 * wy0 : 0.f;
    cidx[t][1] = (y0c * 64 + x1c) * DH_; cw[t][1] = (vx1 & vy0) ? wx1 * wy0 : 0.f;
    cidx[t][2] = (y1c * 64 + x0c) * DH_; cw[t][2] = (vx0 & vy1) ? wx0 * wy1 : 0.f;
    cidx[t][3] = (y1c * 64 + x1c) * DH_; cw[t][3] = (vx1 & vy1) ? wx1 * wy1 : 0.f;
  }
  if (t < 8) {
    const float* pr = proj + (size_t)row * 216 + 144 + t * 9;
    float lg[9], mx = -1e30f;
#pragma unroll
    for (int p = 0; p < 9; ++p) { lg[p] = pr[p]; mx = fmaxf(mx, lg[p]); }
    float s = 0.f;
#pragma unroll
    for (int p = 0; p < 9; ++p) { lg[p] = __expf(lg[p] - mx); s += lg[p]; }
    float inv = 1.f / s;
#pragma unroll
    for (int p = 0; p < 9; ++p) sa[t * 9 + p] = lg[p] * inv;
  }
  __syncthreads();

  const int h = t >> 5, d = t & 31;
  const float* vb = valsum + (((size_t)(b * NH_ + h) << 12)) * DH_ + d;
  float acc = 0.f;
#pragma unroll
  for (int p = 0; p < 9; ++p) {
    const int hp = h * 9 + p;
    float s = 0.f;
#pragma unroll
    for (int k = 0; k < 4; ++k) s += cw[hp][k] * vb[cidx[hp][k]];
    acc += sa[hp] * s;
  }
  unsigned short hv = f2bf(acc);
  ihi[(size_t)row * 256 + t] = hv;
  ilo[(size_t)row * 256 + t] = f2bf(acc - bf2f(hv));
}

extern "C" void kernel_launch(void* const* d_in, const int* in_sizes, int n_in,
                              void* d_out, int out_size, void* d_ws, size_t ws_size,
                              hipStream_t stream) {
  const float* x      = (const float*)d_in[0];
  const float* W_off  = (const float*)d_in[1];
  const float* b_off  = (const float*)d_in[2];
  const float* W_attn = (const float*)d_in[3];
  const float* b_attn = (const float*)d_in[4];
  const float* W_v    = (const float*)d_in[5];
  const float* b_v    = (const float*)d_in[6];
  const float* W_o    = (const float*)d_in[7];
  const float* b_o    = (const float*)d_in[8];
  float* out = (float*)d_out;

  // ---- workspace layout
  float* valsum = (float*)d_ws;                       // 16384*256   f32
  float* proj   = valsum + (size_t)MM_ * 256;         // 16384*216   f32
  float* bcat   = proj + (size_t)MM_ * 216;           // 256         f32
  unsigned short* ash = (unsigned short*)(bcat + 256);  // 16384*256 bf16
  unsigned short* asl = ash + (size_t)MM_ * 256;
  unsigned short* wvh = asl + (size_t)MM_ * 256;        // 256*256
  unsigned short* wvl = wvh + 65536;
  unsigned short* wch = wvl + 65536;                    // 216*256
  unsigned short* wcl = wch + 55296;
  unsigned short* woh = wcl + 55296;                    // 256*256
  unsigned short* wol = woh + 65536;
  // inter aliases asum (asum dead after mgemm<0>)
  unsigned short* ihi = ash;
  unsigned short* ilo = asl;

  dim3 blk(256);
  prep_w<<<dim3(256), blk, 0, stream>>>(W_off, W_attn, W_v, W_o, b_off, b_attn,
                                        wvh, wvl, wch, wcl, woh, wol, bcat);
  prep_a<<<dim3(MM_ / 4), blk, 0, stream>>>(x, ash, asl);
  mgemm<0><<<dim3(128, 2), blk, 0, stream>>>(ash, asl, nullptr, wvh, wvl, b_v, valsum);
  mgemm<1><<<dim3(128, 2), blk, 0, stream>>>(nullptr, nullptr, x, wch, wcl, bcat, proj);
  sample_k<<<dim3(MM_), blk, 0, stream>>>(valsum, proj, ihi, ilo);
  mgemm<2><<<dim3(128, 2), blk, 0, stream>>>(ihi, ilo, nullptr, woh, wol, b_o, out);
}

// Round 4
// 176.501 us; speedup vs baseline: 1.7977x; 1.0861x over previous
//
#include <hip/hip_runtime.h>
#include <hip/hip_bf16.h>

// DeformableTemporalAttention — MI355X (gfx950)
// B=4, N=4096 (64x64), T=3, D=256, H=8, P=9, dh=32
//
// Pipeline (5 dispatches):
//  1. prep_w  : transpose+split weights to bf16 hi/lo [n][k]; pack bcat
//  2. prep_a  : asum = sum_t x -> bf16 hi/lo [M][256]
//  3. mgemm01 : fused  valsum = asum @ W_v + 3*b_v   (blocks y=0,1)
//                      proj   = x_mid @ [W_off|W_attn] + bcat (blocks y=2,3)
//               MFMA 3-pass bf16 hi/lo split, BM=64 BN=128 BK=64, 3 blocks/CU
//  4. sample_k: 1 wave per pixel, float4 gathers -> inter bf16 hi/lo
//  5. mgemm2  : out = inter @ W_o + b_o

#define NH_ 8
#define DH_ 32
#define MM_ 16384   // B*N

typedef __attribute__((ext_vector_type(8))) short bf16x8;
typedef __attribute__((ext_vector_type(4))) short bf16x4;
typedef __attribute__((ext_vector_type(4))) float f32x4;

static __device__ __forceinline__ unsigned short f2bf(float f) {
  unsigned int u = __float_as_uint(f);
  u = (u + 0x7fff + ((u >> 16) & 1)) >> 16;   // RN-even
  return (unsigned short)u;
}
static __device__ __forceinline__ float bf2f(unsigned short h) {
  return __uint_as_float(((unsigned int)h) << 16);
}

// ---------------- prep_w: weights -> transposed bf16 hi/lo ----------------
__global__ __launch_bounds__(256) void prep_w(
    const float* __restrict__ W_off, const float* __restrict__ W_attn,
    const float* __restrict__ W_v, const float* __restrict__ W_o,
    const float* __restrict__ b_off, const float* __restrict__ b_attn,
    unsigned short* __restrict__ wvh, unsigned short* __restrict__ wvl,
    unsigned short* __restrict__ wch, unsigned short* __restrict__ wcl,
    unsigned short* __restrict__ woh, unsigned short* __restrict__ wol,
    float* __restrict__ bcat) {
  const int n = blockIdx.x, t = threadIdx.x;
  {
    float v = W_v[(size_t)t * 256 + n];
    unsigned short h = f2bf(v);
    wvh[n * 256 + t] = h; wvl[n * 256 + t] = f2bf(v - bf2f(h));
  }
  {
    float v = W_o[(size_t)t * 256 + n];
    unsigned short h = f2bf(v);
    woh[n * 256 + t] = h; wol[n * 256 + t] = f2bf(v - bf2f(h));
  }
  if (n < 216) {
    float v = (n < 144) ? W_off[(size_t)t * 144 + n] : W_attn[(size_t)t * 72 + (n - 144)];
    unsigned short h = f2bf(v);
    wch[n * 256 + t] = h; wcl[n * 256 + t] = f2bf(v - bf2f(h));
  }
  if (n == 0 && t < 216) bcat[t] = (t < 144) ? b_off[t] : b_attn[t - 144];
}

// ---------------- prep_a: asum = sum_t x -> bf16 hi/lo [M][256] -----------
__global__ __launch_bounds__(256) void prep_a(const float* __restrict__ x,
                                              unsigned short* __restrict__ ash,
                                              unsigned short* __restrict__ asl) {
  const int gid = blockIdx.x * 256 + threadIdx.x;   // 0 .. M*64-1
  const int row = gid >> 6, c4 = (gid & 63) * 4;
  const float* xr = x + (size_t)row * 768 + c4;
  float4 a0 = *(const float4*)xr;
  float4 a1 = *(const float4*)(xr + 256);
  float4 a2 = *(const float4*)(xr + 512);
  float s[4] = {a0.x + a1.x + a2.x, a0.y + a1.y + a2.y,
                a0.z + a1.z + a2.z, a0.w + a1.w + a2.w};
  bf16x4 hv, lv;
#pragma unroll
  for (int j = 0; j < 4; ++j) {
    unsigned short h = f2bf(s[j]);
    hv[j] = (short)h;
    lv[j] = (short)f2bf(s[j] - bf2f(h));
  }
  *(bf16x4*)(ash + (size_t)row * 256 + c4) = hv;
  *(bf16x4*)(asl + (size_t)row * 256 + c4) = lv;
}

// ---------------- fused GEMM: valsum (y=0,1) + proj (y=2,3) ----------------
// BM=64, BN=128, BK=64; 256 thr = 4 waves (2x2), each wave 32x64 (frag 2x4).
__global__ __launch_bounds__(256) void mgemm01(
    const unsigned short* __restrict__ Ahi, const unsigned short* __restrict__ Alo,
    const float* __restrict__ X,
    const unsigned short* __restrict__ Wvh, const unsigned short* __restrict__ Wvl,
    const unsigned short* __restrict__ Wch, const unsigned short* __restrict__ Wcl,
    const float* __restrict__ b_v, const float* __restrict__ bcat,
    float* __restrict__ valsum, float* __restrict__ proj) {
  __shared__ unsigned short Ah[64][64], Al[64][64], Bh[128][64], Bl[128][64];
  const int mode1 = (blockIdx.y >= 2);
  const int n0 = (blockIdx.y & 1) * 128;
  const int m0 = blockIdx.x * 64;
  const int tid = threadIdx.x;
  const int wid = tid >> 6, lane = tid & 63;
  const int am = (wid >> 1) * 32, bn = (wid & 1) * 64;
  const int fr = lane & 15, kg = lane >> 4;
  const unsigned short* Bth = mode1 ? Wch : Wvh;
  const unsigned short* Btl = mode1 ? Wcl : Wvl;

  f32x4 acc[2][4];
#pragma unroll
  for (int i = 0; i < 2; ++i)
#pragma unroll
    for (int j = 0; j < 4; ++j) acc[i][j] = (f32x4)(0.f);

  for (int k0 = 0; k0 < 256; k0 += 64) {
    // ---- stage A (64 x 64) hi/lo
#pragma unroll
    for (int i = 0; i < 2; ++i) {
      int cid = i * 256 + tid;
      int r = cid >> 3, c = cid & 7;
      int dst = r * 64 + ((c ^ (r & 7)) * 8);
      bf16x8 hv, lv;
      if (mode1) {
        const float* src = X + ((size_t)(m0 + r) * 3 + 1) * 256 + k0 + c * 8;
        float4 f0 = *(const float4*)src, f1 = *(const float4*)(src + 4);
        float vv[8] = {f0.x, f0.y, f0.z, f0.w, f1.x, f1.y, f1.z, f1.w};
#pragma unroll
        for (int j = 0; j < 8; ++j) {
          unsigned short h = f2bf(vv[j]);
          hv[j] = (short)h;
          lv[j] = (short)f2bf(vv[j] - bf2f(h));
        }
      } else {
        size_t off = (size_t)(m0 + r) * 256 + k0 + c * 8;
        hv = *(const bf16x8*)(Ahi + off);
        lv = *(const bf16x8*)(Alo + off);
      }
      *(bf16x8*)(&Ah[0][0] + dst) = hv;
      *(bf16x8*)(&Al[0][0] + dst) = lv;
    }
    // ---- stage B (128 x 64) hi/lo
#pragma unroll
    for (int i = 0; i < 4; ++i) {
      int cid = i * 256 + tid;
      int r = cid >> 3, c = cid & 7;
      int dst = r * 64 + ((c ^ (r & 7)) * 8);
      int nrow = n0 + r;
      bf16x8 hv = (bf16x8)(short)0, lv = (bf16x8)(short)0;
      if (!mode1 || nrow < 216) {
        size_t off = (size_t)nrow * 256 + k0 + c * 8;
        hv = *(const bf16x8*)(Bth + off);
        lv = *(const bf16x8*)(Btl + off);
      }
      *(bf16x8*)(&Bh[0][0] + dst) = hv;
      *(bf16x8*)(&Bl[0][0] + dst) = lv;
    }
    __syncthreads();

#pragma unroll
    for (int ks = 0; ks < 2; ++ks) {
      const int kc = ks * 4 + kg;
      bf16x8 ah[2], al[2], bh[4], bl[4];
#pragma unroll
      for (int mi = 0; mi < 2; ++mi) {
        int m = am + mi * 16 + fr;
        int o = m * 64 + ((kc ^ (m & 7)) * 8);
        ah[mi] = *(const bf16x8*)(&Ah[0][0] + o);
        al[mi] = *(const bf16x8*)(&Al[0][0] + o);
      }
#pragma unroll
      for (int ni = 0; ni < 4; ++ni) {
        int n = bn + ni * 16 + fr;
        int o = n * 64 + ((kc ^ (n & 7)) * 8);
        bh[ni] = *(const bf16x8*)(&Bh[0][0] + o);
        bl[ni] = *(const bf16x8*)(&Bl[0][0] + o);
      }
#pragma unroll
      for (int mi = 0; mi < 2; ++mi)
#pragma unroll
        for (int ni = 0; ni < 4; ++ni) {
          acc[mi][ni] = __builtin_amdgcn_mfma_f32_16x16x32_bf16(ah[mi], bh[ni], acc[mi][ni], 0, 0, 0);
          acc[mi][ni] = __builtin_amdgcn_mfma_f32_16x16x32_bf16(ah[mi], bl[ni], acc[mi][ni], 0, 0, 0);
          acc[mi][ni] = __builtin_amdgcn_mfma_f32_16x16x32_bf16(al[mi], bh[ni], acc[mi][ni], 0, 0, 0);
        }
    }
    __syncthreads();
  }

  // ---- epilogue: C layout col=lane&15, row=(lane>>4)*4+reg
  const int ro = kg * 4;
#pragma unroll
  for (int mi = 0; mi < 2; ++mi)
#pragma unroll
    for (int ni = 0; ni < 4; ++ni) {
      int col = n0 + bn + ni * 16 + fr;
      if (mode1 && col >= 216) continue;
      int rowb = m0 + am + mi * 16 + ro;
      float bv = mode1 ? bcat[col] : b_v[col] * 3.f;
#pragma unroll
      for (int r = 0; r < 4; ++r) {
        int grow = rowb + r;
        float v = acc[mi][ni][r] + bv;
        if (mode1) {
          proj[(size_t)grow * 216 + col] = v;
        } else {
          int b = grow >> 12, nn = grow & 4095;
          int h = col >> 5, d = col & 31;
          valsum[(((size_t)(b * NH_ + h) << 12) + nn) * DH_ + d] = v;
        }
      }
    }
}

// ---------------- O-GEMM: out = inter @ W_o + b_o --------------------------
__global__ __launch_bounds__(256) void mgemm2(
    const unsigned short* __restrict__ Ahi, const unsigned short* __restrict__ Alo,
    const unsigned short* __restrict__ Bth, const unsigned short* __restrict__ Btl,
    const float* __restrict__ bias, float* __restrict__ Cout) {
  __shared__ unsigned short Ah[64][64], Al[64][64], Bh[128][64], Bl[128][64];
  const int n0 = blockIdx.y * 128;
  const int m0 = blockIdx.x * 64;
  const int tid = threadIdx.x;
  const int wid = tid >> 6, lane = tid & 63;
  const int am = (wid >> 1) * 32, bn = (wid & 1) * 64;
  const int fr = lane & 15, kg = lane >> 4;

  f32x4 acc[2][4];
#pragma unroll
  for (int i = 0; i < 2; ++i)
#pragma unroll
    for (int j = 0; j < 4; ++j) acc[i][j] = (f32x4)(0.f);

  for (int k0 = 0; k0 < 256; k0 += 64) {
#pragma unroll
    for (int i = 0; i < 2; ++i) {
      int cid = i * 256 + tid;
      int r = cid >> 3, c = cid & 7;
      int dst = r * 64 + ((c ^ (r & 7)) * 8);
      size_t off = (size_t)(m0 + r) * 256 + k0 + c * 8;
      *(bf16x8*)(&Ah[0][0] + dst) = *(const bf16x8*)(Ahi + off);
      *(bf16x8*)(&Al[0][0] + dst) = *(const bf16x8*)(Alo + off);
    }
#pragma unroll
    for (int i = 0; i < 4; ++i) {
      int cid = i * 256 + tid;
      int r = cid >> 3, c = cid & 7;
      int dst = r * 64 + ((c ^ (r & 7)) * 8);
      size_t off = (size_t)(n0 + r) * 256 + k0 + c * 8;
      *(bf16x8*)(&Bh[0][0] + dst) = *(const bf16x8*)(Bth + off);
      *(bf16x8*)(&Bl[0][0] + dst) = *(const bf16x8*)(Btl + off);
    }
    __syncthreads();

#pragma unroll
    for (int ks = 0; ks < 2; ++ks) {
      const int kc = ks * 4 + kg;
      bf16x8 ah[2], al[2], bh[4], bl[4];
#pragma unroll
      for (int mi = 0; mi < 2; ++mi) {
        int m = am + mi * 16 + fr;
        int o = m * 64 + ((kc ^ (m & 7)) * 8);
        ah[mi] = *(const bf16x8*)(&Ah[0][0] + o);
        al[mi] = *(const bf16x8*)(&Al[0][0] + o);
      }
#pragma unroll
      for (int ni = 0; ni < 4; ++ni) {
        int n = bn + ni * 16 + fr;
        int o = n * 64 + ((kc ^ (n & 7)) * 8);
        bh[ni] = *(const bf16x8*)(&Bh[0][0] + o);
        bl[ni] = *(const bf16x8*)(&Bl[0][0] + o);
      }
#pragma unroll
      for (int mi = 0; mi < 2; ++mi)
#pragma unroll
        for (int ni = 0; ni < 4; ++ni) {
          acc[mi][ni] = __builtin_amdgcn_mfma_f32_16x16x32_bf16(ah[mi], bh[ni], acc[mi][ni], 0, 0, 0);
          acc[mi][ni] = __builtin_amdgcn_mfma_f32_16x16x32_bf16(ah[mi], bl[ni], acc[mi][ni], 0, 0, 0);
          acc[mi][ni] = __builtin_amdgcn_mfma_f32_16x16x32_bf16(al[mi], bh[ni], acc[mi][ni], 0, 0, 0);
        }
    }
    __syncthreads();
  }

  const int ro = kg * 4;
#pragma unroll
  for (int mi = 0; mi < 2; ++mi)
#pragma unroll
    for (int ni = 0; ni < 4; ++ni) {
      int col = n0 + bn + ni * 16 + fr;
      int rowb = m0 + am + mi * 16 + ro;
      float bv = bias[col];
#pragma unroll
      for (int r = 0; r < 4; ++r)
        Cout[(size_t)(rowb + r) * 256 + col] = acc[mi][ni][r] + bv;
    }
}

// ---------------- sampler: 1 wave per pixel, float4 gathers ----------------
__global__ __launch_bounds__(64) void sample_k(const float* __restrict__ valsum,
                                               const float* __restrict__ proj,
                                               unsigned short* __restrict__ ihi,
                                               unsigned short* __restrict__ ilo) {
  const int bid = blockIdx.x;
  const int row = ((bid & 7) << 11) + (bid >> 3);   // XCD-chunked (16384 % 8 == 0)
  const int b = row >> 12, n = row & 4095;

  __shared__ int cidx[72][4];
  __shared__ float cw[72][4];
  __shared__ float sa[72];

  const int t = threadIdx.x;
  const float* pr = proj + (size_t)row * 216;
  for (int e = t; e < 72; e += 64) {
    float ox = pr[e * 2], oy = pr[e * 2 + 1];
    float gx = (float)(n & 63) + ox * 31.5f;
    float gy = (float)(n >> 6) + oy * 31.5f;
    float fx0 = floorf(gx), fy0 = floorf(gy);
    float wx1 = gx - fx0, wy1 = gy - fy0;
    float wx0 = 1.f - wx1, wy0 = 1.f - wy1;
    int x0 = (int)fx0, y0 = (int)fy0, x1 = x0 + 1, y1 = y0 + 1;
    bool vx0 = (x0 >= 0) & (x0 < 64), vx1 = (x1 >= 0) & (x1 < 64);
    bool vy0 = (y0 >= 0) & (y0 < 64), vy1 = (y1 >= 0) & (y1 < 64);
    int x0c = min(max(x0, 0), 63), x1c = min(max(x1, 0), 63);
    int y0c = min(max(y0, 0), 63), y1c = min(max(y1, 0), 63);
    cidx[e][0] = (y0c * 64 + x0c) * DH_; cw[e][0] = (vx0 & vy0) ? wx0 * wy0 : 0.f;
    cidx[e][1] = (y0c * 64 + x1c) * DH_; cw[e][1] = (vx1 & vy0) ? wx1 * wy0 : 0.f;
    cidx[e][2] = (y1c * 64 + x0c) * DH_; cw[e][2] = (vx0 & vy1) ? wx0 * wy1 : 0.f;
    cidx[e][3] = (y1c * 64 + x1c) * DH_; cw[e][3] = (vx1 & vy1) ? wx1 * wy1 : 0.f;
  }
  if (t < 8) {
    const float* pa = pr + 144 + t * 9;
    float lg[9], mx = -1e30f;
#pragma unroll
    for (int p = 0; p < 9; ++p) { lg[p] = pa[p]; mx = fmaxf(mx, lg[p]); }
    float s = 0.f;
#pragma unroll
    for (int p = 0; p < 9; ++p) { lg[p] = __expf(lg[p] - mx); s += lg[p]; }
    float inv = 1.f / s;
#pragma unroll
    for (int p = 0; p < 9; ++p) sa[t * 9 + p] = lg[p] * inv;
  }
  __syncthreads();

  const int h = t >> 3, d4 = (t & 7) * 4;
  const float* vb = valsum + ((size_t)((b * NH_ + h) << 12)) * DH_ + d4;
  float ax = 0.f, ay = 0.f, az = 0.f, aw = 0.f;
#pragma unroll
  for (int p = 0; p < 9; ++p) {
    const int hp = h * 9 + p;
    float sx = 0.f, sy = 0.f, sz = 0.f, sw = 0.f;
#pragma unroll
    for (int c = 0; c < 4; ++c) {
      float4 v = *(const float4*)(vb + cidx[hp][c]);
      float w = cw[hp][c];
      sx += w * v.x; sy += w * v.y; sz += w * v.z; sw += w * v.w;
    }
    float ap = sa[hp];
    ax += ap * sx; ay += ap * sy; az += ap * sz; aw += ap * sw;
  }
  float av[4] = {ax, ay, az, aw};
  bf16x4 hv, lv;
#pragma unroll
  for (int j = 0; j < 4; ++j) {
    unsigned short hh = f2bf(av[j]);
    hv[j] = (short)hh;
    lv[j] = (short)f2bf(av[j] - bf2f(hh));
  }
  const size_t o = (size_t)row * 256 + t * 4;
  *(bf16x4*)(ihi + o) = hv;
  *(bf16x4*)(ilo + o) = lv;
}

extern "C" void kernel_launch(void* const* d_in, const int* in_sizes, int n_in,
                              void* d_out, int out_size, void* d_ws, size_t ws_size,
                              hipStream_t stream) {
  const float* x      = (const float*)d_in[0];
  const float* W_off  = (const float*)d_in[1];
  const float* b_off  = (const float*)d_in[2];
  const float* W_attn = (const float*)d_in[3];
  const float* b_attn = (const float*)d_in[4];
  const float* W_v    = (const float*)d_in[5];
  const float* b_v    = (const float*)d_in[6];
  const float* W_o    = (const float*)d_in[7];
  const float* b_o    = (const float*)d_in[8];
  float* out = (float*)d_out;

  // ---- workspace layout
  float* valsum = (float*)d_ws;                         // 16384*256 f32
  float* proj   = valsum + (size_t)MM_ * 256;           // 16384*216 f32
  float* bcat   = proj + (size_t)MM_ * 216;             // 256 f32
  unsigned short* ash = (unsigned short*)(bcat + 256);  // 16384*256 bf16
  unsigned short* asl = ash + (size_t)MM_ * 256;
  unsigned short* wvh = asl + (size_t)MM_ * 256;        // 256*256
  unsigned short* wvl = wvh + 65536;
  unsigned short* wch = wvl + 65536;                    // 216*256
  unsigned short* wcl = wch + 55296;
  unsigned short* woh = wcl + 55296;                    // 256*256
  unsigned short* wol = woh + 65536;
  // inter aliases asum (asum dead after mgemm01)
  unsigned short* ihi = ash;
  unsigned short* ilo = asl;

  prep_w<<<dim3(256), dim3(256), 0, stream>>>(W_off, W_attn, W_v, W_o, b_off, b_attn,
                                              wvh, wvl, wch, wcl, woh, wol, bcat);
  prep_a<<<dim3(MM_ / 4), dim3(256), 0, stream>>>(x, ash, asl);
  mgemm01<<<dim3(256, 4), dim3(256), 0, stream>>>(ash, asl, x, wvh, wvl, wch, wcl,
                                                  b_v, bcat, valsum, proj);
  sample_k<<<dim3(MM_), dim3(64), 0, stream>>>(valsum, proj, ihi, ilo);
  mgemm2<<<dim3(256, 2), dim3(256), 0, stream>>>(ihi, ilo, woh, wol, b_o, out);
}

// Round 5
// 174.550 us; speedup vs baseline: 1.8177x; 1.0112x over previous
//
#include <hip/hip_runtime.h>
#include <hip/hip_bf16.h>

// DeformableTemporalAttention — MI355X (gfx950)
// B=4, N=4096 (64x64), T=3, D=256, H=8, P=9, dh=32
//
// Pipeline (4 dispatches):
//  1. prep    : asum = sum_t x -> bf16 hi/lo;  xmid = x[:,:,1,:] -> bf16 hi/lo;
//               weights transposed+split to bf16 hi/lo [n][k]; bcat packed
//  2. mgemm01 : fused  valsum = asum @ W_v + 3*b_v     (blocks y=0,1)
//                      proj   = xmid @ [W_off|W_attn] + bcat (blocks y=2,3)
//               MFMA 3-pass bf16 hi/lo split, BM=64 BN=128 BK=64
//  3. sample4 : 4 pixels / 256-thr block (warp-private tables), float4 gathers
//  4. mgemm2  : out = inter @ W_o + b_o

#define NH_ 8
#define DH_ 32
#define MM_ 16384   // B*N

typedef __attribute__((ext_vector_type(8))) short bf16x8;
typedef __attribute__((ext_vector_type(4))) short bf16x4;
typedef __attribute__((ext_vector_type(4))) float f32x4;

static __device__ __forceinline__ unsigned short f2bf(float f) {
  unsigned int u = __float_as_uint(f);
  u = (u + 0x7fff + ((u >> 16) & 1)) >> 16;   // RN-even
  return (unsigned short)u;
}
static __device__ __forceinline__ float bf2f(unsigned short h) {
  return __uint_as_float(((unsigned int)h) << 16);
}

// ---------------- prep: A-side splits + weight transpose/splits ------------
// blocks 0..4095: asum/xmid hi-lo (thread = 4 consecutive k of one row)
// blocks 4096..4351: weight transpose (block = n, thread = k)
__global__ __launch_bounds__(256) void prep(
    const float* __restrict__ x,
    const float* __restrict__ W_off, const float* __restrict__ W_attn,
    const float* __restrict__ W_v, const float* __restrict__ W_o,
    const float* __restrict__ b_off, const float* __restrict__ b_attn,
    unsigned short* __restrict__ ash, unsigned short* __restrict__ asl,
    unsigned short* __restrict__ xmh, unsigned short* __restrict__ xml,
    unsigned short* __restrict__ wvh, unsigned short* __restrict__ wvl,
    unsigned short* __restrict__ wch, unsigned short* __restrict__ wcl,
    unsigned short* __restrict__ woh, unsigned short* __restrict__ wol,
    float* __restrict__ bcat) {
  const int bid = blockIdx.x, t = threadIdx.x;
  if (bid < 4096) {
    const int gid = bid * 256 + t;
    const int row = gid >> 6, c4 = (gid & 63) * 4;
    const float* xr = x + (size_t)row * 768 + c4;
    float4 a0 = *(const float4*)xr;
    float4 a1 = *(const float4*)(xr + 256);
    float4 a2 = *(const float4*)(xr + 512);
    float s[4] = {a0.x + a1.x + a2.x, a0.y + a1.y + a2.y,
                  a0.z + a1.z + a2.z, a0.w + a1.w + a2.w};
    float m[4] = {a1.x, a1.y, a1.z, a1.w};
    bf16x4 shv, slv, mhv, mlv;
#pragma unroll
    for (int j = 0; j < 4; ++j) {
      unsigned short h = f2bf(s[j]);
      shv[j] = (short)h; slv[j] = (short)f2bf(s[j] - bf2f(h));
      unsigned short h2 = f2bf(m[j]);
      mhv[j] = (short)h2; mlv[j] = (short)f2bf(m[j] - bf2f(h2));
    }
    const size_t o = (size_t)row * 256 + c4;
    *(bf16x4*)(ash + o) = shv;  *(bf16x4*)(asl + o) = slv;
    *(bf16x4*)(xmh + o) = mhv;  *(bf16x4*)(xml + o) = mlv;
  } else {
    const int n = bid - 4096;
    {
      float v = W_v[(size_t)t * 256 + n];
      unsigned short h = f2bf(v);
      wvh[n * 256 + t] = h; wvl[n * 256 + t] = f2bf(v - bf2f(h));
    }
    {
      float v = W_o[(size_t)t * 256 + n];
      unsigned short h = f2bf(v);
      woh[n * 256 + t] = h; wol[n * 256 + t] = f2bf(v - bf2f(h));
    }
    if (n < 216) {
      float v = (n < 144) ? W_off[(size_t)t * 144 + n] : W_attn[(size_t)t * 72 + (n - 144)];
      unsigned short h = f2bf(v);
      wch[n * 256 + t] = h; wcl[n * 256 + t] = f2bf(v - bf2f(h));
    }
    if (n == 0 && t < 216) bcat[t] = (t < 144) ? b_off[t] : b_attn[t - 144];
  }
}

// ---------------- fused GEMM: valsum (y=0,1) + proj (y=2,3) ----------------
// BM=64, BN=128, BK=64; 256 thr = 4 waves (2x2), each wave 32x64 (frag 2x4).
__global__ __launch_bounds__(256) void mgemm01(
    const unsigned short* __restrict__ Ahi, const unsigned short* __restrict__ Alo,
    const unsigned short* __restrict__ Xmh, const unsigned short* __restrict__ Xml,
    const unsigned short* __restrict__ Wvh, const unsigned short* __restrict__ Wvl,
    const unsigned short* __restrict__ Wch, const unsigned short* __restrict__ Wcl,
    const float* __restrict__ b_v, const float* __restrict__ bcat,
    float* __restrict__ valsum, float* __restrict__ proj) {
  __shared__ unsigned short Ah[64][64], Al[64][64], Bh[128][64], Bl[128][64];
  const int mode1 = (blockIdx.y >= 2);
  const int n0 = (blockIdx.y & 1) * 128;
  const int m0 = blockIdx.x * 64;
  const int tid = threadIdx.x;
  const int wid = tid >> 6, lane = tid & 63;
  const int am = (wid >> 1) * 32, bn = (wid & 1) * 64;
  const int fr = lane & 15, kg = lane >> 4;
  const unsigned short* Asrch = mode1 ? Xmh : Ahi;
  const unsigned short* Asrcl = mode1 ? Xml : Alo;
  const unsigned short* Bth = mode1 ? Wch : Wvh;
  const unsigned short* Btl = mode1 ? Wcl : Wvl;

  f32x4 acc[2][4];
#pragma unroll
  for (int i = 0; i < 2; ++i)
#pragma unroll
    for (int j = 0; j < 4; ++j) acc[i][j] = (f32x4)(0.f);

  for (int k0 = 0; k0 < 256; k0 += 64) {
    // ---- stage A (64 x 64) hi/lo
#pragma unroll
    for (int i = 0; i < 2; ++i) {
      int cid = i * 256 + tid;
      int r = cid >> 3, c = cid & 7;
      int dst = r * 64 + ((c ^ (r & 7)) * 8);
      size_t off = (size_t)(m0 + r) * 256 + k0 + c * 8;
      *(bf16x8*)(&Ah[0][0] + dst) = *(const bf16x8*)(Asrch + off);
      *(bf16x8*)(&Al[0][0] + dst) = *(const bf16x8*)(Asrcl + off);
    }
    // ---- stage B (128 x 64) hi/lo
#pragma unroll
    for (int i = 0; i < 4; ++i) {
      int cid = i * 256 + tid;
      int r = cid >> 3, c = cid & 7;
      int dst = r * 64 + ((c ^ (r & 7)) * 8);
      int nrow = n0 + r;
      bf16x8 hv = (bf16x8)(short)0, lv = (bf16x8)(short)0;
      if (!mode1 || nrow < 216) {
        size_t off = (size_t)nrow * 256 + k0 + c * 8;
        hv = *(const bf16x8*)(Bth + off);
        lv = *(const bf16x8*)(Btl + off);
      }
      *(bf16x8*)(&Bh[0][0] + dst) = hv;
      *(bf16x8*)(&Bl[0][0] + dst) = lv;
    }
    __syncthreads();

#pragma unroll
    for (int ks = 0; ks < 2; ++ks) {
      const int kc = ks * 4 + kg;
      bf16x8 ah[2], al[2], bh[4], bl[4];
#pragma unroll
      for (int mi = 0; mi < 2; ++mi) {
        int m = am + mi * 16 + fr;
        int o = m * 64 + ((kc ^ (m & 7)) * 8);
        ah[mi] = *(const bf16x8*)(&Ah[0][0] + o);
        al[mi] = *(const bf16x8*)(&Al[0][0] + o);
      }
#pragma unroll
      for (int ni = 0; ni < 4; ++ni) {
        int n = bn + ni * 16 + fr;
        int o = n * 64 + ((kc ^ (n & 7)) * 8);
        bh[ni] = *(const bf16x8*)(&Bh[0][0] + o);
        bl[ni] = *(const bf16x8*)(&Bl[0][0] + o);
      }
#pragma unroll
      for (int mi = 0; mi < 2; ++mi)
#pragma unroll
        for (int ni = 0; ni < 4; ++ni) {
          acc[mi][ni] = __builtin_amdgcn_mfma_f32_16x16x32_bf16(ah[mi], bh[ni], acc[mi][ni], 0, 0, 0);
          acc[mi][ni] = __builtin_amdgcn_mfma_f32_16x16x32_bf16(ah[mi], bl[ni], acc[mi][ni], 0, 0, 0);
          acc[mi][ni] = __builtin_amdgcn_mfma_f32_16x16x32_bf16(al[mi], bh[ni], acc[mi][ni], 0, 0, 0);
        }
    }
    __syncthreads();
  }

  // ---- epilogue: C layout col=lane&15, row=(lane>>4)*4+reg
  const int ro = kg * 4;
#pragma unroll
  for (int mi = 0; mi < 2; ++mi)
#pragma unroll
    for (int ni = 0; ni < 4; ++ni) {
      int col = n0 + bn + ni * 16 + fr;
      if (mode1 && col >= 216) continue;
      int rowb = m0 + am + mi * 16 + ro;
      float bv = mode1 ? bcat[col] : b_v[col] * 3.f;
#pragma unroll
      for (int r = 0; r < 4; ++r) {
        int grow = rowb + r;
        float v = acc[mi][ni][r] + bv;
        if (mode1) {
          proj[(size_t)grow * 216 + col] = v;
        } else {
          int b = grow >> 12, nn = grow & 4095;
          int h = col >> 5, d = col & 31;
          valsum[(((size_t)(b * NH_ + h) << 12) + nn) * DH_ + d] = v;
        }
      }
    }
}

// ---------------- O-GEMM: out = inter @ W_o + b_o --------------------------
__global__ __launch_bounds__(256) void mgemm2(
    const unsigned short* __restrict__ Ahi, const unsigned short* __restrict__ Alo,
    const unsigned short* __restrict__ Bth, const unsigned short* __restrict__ Btl,
    const float* __restrict__ bias, float* __restrict__ Cout) {
  __shared__ unsigned short Ah[64][64], Al[64][64], Bh[128][64], Bl[128][64];
  const int n0 = blockIdx.y * 128;
  const int m0 = blockIdx.x * 64;
  const int tid = threadIdx.x;
  const int wid = tid >> 6, lane = tid & 63;
  const int am = (wid >> 1) * 32, bn = (wid & 1) * 64;
  const int fr = lane & 15, kg = lane >> 4;

  f32x4 acc[2][4];
#pragma unroll
  for (int i = 0; i < 2; ++i)
#pragma unroll
    for (int j = 0; j < 4; ++j) acc[i][j] = (f32x4)(0.f);

  for (int k0 = 0; k0 < 256; k0 += 64) {
#pragma unroll
    for (int i = 0; i < 2; ++i) {
      int cid = i * 256 + tid;
      int r = cid >> 3, c = cid & 7;
      int dst = r * 64 + ((c ^ (r & 7)) * 8);
      size_t off = (size_t)(m0 + r) * 256 + k0 + c * 8;
      *(bf16x8*)(&Ah[0][0] + dst) = *(const bf16x8*)(Ahi + off);
      *(bf16x8*)(&Al[0][0] + dst) = *(const bf16x8*)(Alo + off);
    }
#pragma unroll
    for (int i = 0; i < 4; ++i) {
      int cid = i * 256 + tid;
      int r = cid >> 3, c = cid & 7;
      int dst = r * 64 + ((c ^ (r & 7)) * 8);
      size_t off = (size_t)(n0 + r) * 256 + k0 + c * 8;
      *(bf16x8*)(&Bh[0][0] + dst) = *(const bf16x8*)(Bth + off);
      *(bf16x8*)(&Bl[0][0] + dst) = *(const bf16x8*)(Btl + off);
    }
    __syncthreads();

#pragma unroll
    for (int ks = 0; ks < 2; ++ks) {
      const int kc = ks * 4 + kg;
      bf16x8 ah[2], al[2], bh[4], bl[4];
#pragma unroll
      for (int mi = 0; mi < 2; ++mi) {
        int m = am + mi * 16 + fr;
        int o = m * 64 + ((kc ^ (m & 7)) * 8);
        ah[mi] = *(const bf16x8*)(&Ah[0][0] + o);
        al[mi] = *(const bf16x8*)(&Al[0][0] + o);
      }
#pragma unroll
      for (int ni = 0; ni < 4; ++ni) {
        int n = bn + ni * 16 + fr;
        int o = n * 64 + ((kc ^ (n & 7)) * 8);
        bh[ni] = *(const bf16x8*)(&Bh[0][0] + o);
        bl[ni] = *(const bf16x8*)(&Bl[0][0] + o);
      }
#pragma unroll
      for (int mi = 0; mi < 2; ++mi)
#pragma unroll
        for (int ni = 0; ni < 4; ++ni) {
          acc[mi][ni] = __builtin_amdgcn_mfma_f32_16x16x32_bf16(ah[mi], bh[ni], acc[mi][ni], 0, 0, 0);
          acc[mi][ni] = __builtin_amdgcn_mfma_f32_16x16x32_bf16(ah[mi], bl[ni], acc[mi][ni], 0, 0, 0);
          acc[mi][ni] = __builtin_amdgcn_mfma_f32_16x16x32_bf16(al[mi], bh[ni], acc[mi][ni], 0, 0, 0);
        }
    }
    __syncthreads();
  }

  const int ro = kg * 4;
#pragma unroll
  for (int mi = 0; mi < 2; ++mi)
#pragma unroll
    for (int ni = 0; ni < 4; ++ni) {
      int col = n0 + bn + ni * 16 + fr;
      int rowb = m0 + am + mi * 16 + ro;
      float bv = bias[col];
#pragma unroll
      for (int r = 0; r < 4; ++r)
        Cout[(size_t)(rowb + r) * 256 + col] = acc[mi][ni][r] + bv;
    }
}

// ---------------- sampler: 4 pixels / 256-thr block, warp-private ----------
__global__ __launch_bounds__(256) void sample4(const float* __restrict__ valsum,
                                               const float* __restrict__ proj,
                                               unsigned short* __restrict__ ihi,
                                               unsigned short* __restrict__ ilo) {
  const int bid = blockIdx.x;                 // 4096 blocks
  const int wv = threadIdx.x >> 6;            // warp -> sub-pixel
  const int lane = threadIdx.x & 63;
  const int row = ((bid & 7) << 11) + ((bid >> 3) << 2) + wv;  // XCD-chunked
  const int b = row >> 12, n = row & 4095;

  __shared__ int cidx[4][72][4];
  __shared__ float cw[4][72][4];
  __shared__ float sa[4][72];

  const float* pr = proj + (size_t)row * 216;
  for (int e = lane; e < 72; e += 64) {
    float ox = pr[e * 2], oy = pr[e * 2 + 1];
    float gx = (float)(n & 63) + ox * 31.5f;
    float gy = (float)(n >> 6) + oy * 31.5f;
    float fx0 = floorf(gx), fy0 = floorf(gy);
    float wx1 = gx - fx0, wy1 = gy - fy0;
    float wx0 = 1.f - wx1, wy0 = 1.f - wy1;
    int x0 = (int)fx0, y0 = (int)fy0, x1 = x0 + 1, y1 = y0 + 1;
    bool vx0 = (x0 >= 0) & (x0 < 64), vx1 = (x1 >= 0) & (x1 < 64);
    bool vy0 = (y0 >= 0) & (y0 < 64), vy1 = (y1 >= 0) & (y1 < 64);
    int x0c = min(max(x0, 0), 63), x1c = min(max(x1, 0), 63);
    int y0c = min(max(y0, 0), 63), y1c = min(max(y1, 0), 63);
    cidx[wv][e][0] = (y0c * 64 + x0c) * DH_; cw[wv][e][0] = (vx0 & vy0) ? wx0 * wy0 : 0.f;
    cidx[wv][e][1] = (y0c * 64 + x1c) * DH_; cw[wv][e][1] = (vx1 & vy0) ? wx1 * wy0 : 0.f;
    cidx[wv][e][2] = (y1c * 64 + x0c) * DH_; cw[wv][e][2] = (vx0 & vy1) ? wx0 * wy1 : 0.f;
    cidx[wv][e][3] = (y1c * 64 + x1c) * DH_; cw[wv][e][3] = (vx1 & vy1) ? wx1 * wy1 : 0.f;
  }
  if (lane < 8) {
    const float* pa = pr + 144 + lane * 9;
    float lg[9], mx = -1e30f;
#pragma unroll
    for (int p = 0; p < 9; ++p) { lg[p] = pa[p]; mx = fmaxf(mx, lg[p]); }
    float s = 0.f;
#pragma unroll
    for (int p = 0; p < 9; ++p) { lg[p] = __expf(lg[p] - mx); s += lg[p]; }
    float inv = 1.f / s;
#pragma unroll
    for (int p = 0; p < 9; ++p) sa[wv][lane * 9 + p] = lg[p] * inv;
  }
  __syncthreads();

  const int h = lane >> 3, d4 = (lane & 7) * 4;
  const float* vb = valsum + ((size_t)((b * NH_ + h) << 12)) * DH_ + d4;
  float ax = 0.f, ay = 0.f, az = 0.f, aw = 0.f;
#pragma unroll
  for (int p = 0; p < 9; ++p) {
    const int hp = h * 9 + p;
    float sx = 0.f, sy = 0.f, sz = 0.f, sw = 0.f;
#pragma unroll
    for (int c = 0; c < 4; ++c) {
      float4 v = *(const float4*)(vb + cidx[wv][hp][c]);
      float w = cw[wv][hp][c];
      sx += w * v.x; sy += w * v.y; sz += w * v.z; sw += w * v.w;
    }
    float ap = sa[wv][hp];
    ax += ap * sx; ay += ap * sy; az += ap * sz; aw += ap * sw;
  }
  float av[4] = {ax, ay, az, aw};
  bf16x4 hv, lv;
#pragma unroll
  for (int j = 0; j < 4; ++j) {
    unsigned short hh = f2bf(av[j]);
    hv[j] = (short)hh;
    lv[j] = (short)f2bf(av[j] - bf2f(hh));
  }
  const size_t o = (size_t)row * 256 + lane * 4;
  *(bf16x4*)(ihi + o) = hv;
  *(bf16x4*)(ilo + o) = lv;
}

extern "C" void kernel_launch(void* const* d_in, const int* in_sizes, int n_in,
                              void* d_out, int out_size, void* d_ws, size_t ws_size,
                              hipStream_t stream) {
  const float* x      = (const float*)d_in[0];
  const float* W_off  = (const float*)d_in[1];
  const float* b_off  = (const float*)d_in[2];
  const float* W_attn = (const float*)d_in[3];
  const float* b_attn = (const float*)d_in[4];
  const float* W_v    = (const float*)d_in[5];
  const float* b_v    = (const float*)d_in[6];
  const float* W_o    = (const float*)d_in[7];
  const float* b_o    = (const float*)d_in[8];
  float* out = (float*)d_out;

  // ---- workspace layout
  float* valsum = (float*)d_ws;                         // 16384*256 f32
  float* proj   = valsum + (size_t)MM_ * 256;           // 16384*216 f32
  float* bcat   = proj + (size_t)MM_ * 216;             // 256 f32
  unsigned short* ash = (unsigned short*)(bcat + 256);  // 16384*256 bf16
  unsigned short* asl = ash + (size_t)MM_ * 256;
  unsigned short* xmh = asl + (size_t)MM_ * 256;        // 16384*256 bf16
  unsigned short* xml = xmh + (size_t)MM_ * 256;
  unsigned short* wvh = xml + (size_t)MM_ * 256;        // 256*256
  unsigned short* wvl = wvh + 65536;
  unsigned short* wch = wvl + 65536;                    // 216*256
  unsigned short* wcl = wch + 55296;
  unsigned short* woh = wcl + 55296;                    // 256*256
  unsigned short* wol = woh + 65536;
  // inter aliases asum (asum dead after mgemm01)
  unsigned short* ihi = ash;
  unsigned short* ilo = asl;

  prep<<<dim3(4352), dim3(256), 0, stream>>>(x, W_off, W_attn, W_v, W_o, b_off, b_attn,
                                             ash, asl, xmh, xml,
                                             wvh, wvl, wch, wcl, woh, wol, bcat);
  mgemm01<<<dim3(256, 4), dim3(256), 0, stream>>>(ash, asl, xmh, xml, wvh, wvl, wch, wcl,
                                                  b_v, bcat, valsum, proj);
  sample4<<<dim3(4096), dim3(256), 0, stream>>>(valsum, proj, ihi, ilo);
  mgemm2<<<dim3(256, 2), dim3(256), 0, stream>>>(ihi, ilo, woh, wol, b_o, out);
}

// Round 6
// 166.252 us; speedup vs baseline: 1.9085x; 1.0499x over previous
//
#include <hip/hip_runtime.h>
#include <hip/hip_bf16.h>

// DeformableTemporalAttention — MI355X (gfx950)
// B=4, N=4096 (64x64), T=3, D=256, H=8, P=9, dh=32
//
// Pipeline (4 dispatches):
//  1. prep    : asum = sum_t x -> bf16 hi/lo;  xmid -> bf16 hi/lo;
//               weights transposed+split to bf16 hi/lo [n][k]; bcat packed
//  2. mgemm01 : fused  valsum = asum @ W_v + 3*b_v     (blocks y=0..3)
//                      proj   = xmid @ [W_off|W_attn] + bcat (y=4..7)
//               BM=BN=BK=64, 32KB LDS, reg-prefetch pipeline, 3-pass bf16 split
//  3. sample4 : 4 pixels / 256-thr block, attn folded into corner weights,
//               batched float4 gathers -> inter (f32)
//  4. mgemm2  : out = inter @ W_o + b_o  (A converted to hi/lo at staging)

#define NH_ 8
#define DH_ 32
#define MM_ 16384   // B*N

typedef __attribute__((ext_vector_type(8))) short bf16x8;
typedef __attribute__((ext_vector_type(4))) short bf16x4;
typedef __attribute__((ext_vector_type(4))) float f32x4;

static __device__ __forceinline__ unsigned short f2bf(float f) {
  unsigned int u = __float_as_uint(f);
  u = (u + 0x7fff + ((u >> 16) & 1)) >> 16;   // RN-even
  return (unsigned short)u;
}
static __device__ __forceinline__ float bf2f(unsigned short h) {
  return __uint_as_float(((unsigned int)h) << 16);
}
static __device__ __forceinline__ void split8(const float4 f0, const float4 f1,
                                              bf16x8& hv, bf16x8& lv) {
  float vv[8] = {f0.x, f0.y, f0.z, f0.w, f1.x, f1.y, f1.z, f1.w};
#pragma unroll
  for (int j = 0; j < 8; ++j) {
    unsigned short h = f2bf(vv[j]);
    hv[j] = (short)h;
    lv[j] = (short)f2bf(vv[j] - bf2f(h));
  }
}

// ---------------- prep: A-side splits + weight transpose/splits ------------
__global__ __launch_bounds__(256) void prep(
    const float* __restrict__ x,
    const float* __restrict__ W_off, const float* __restrict__ W_attn,
    const float* __restrict__ W_v, const float* __restrict__ W_o,
    const float* __restrict__ b_off, const float* __restrict__ b_attn,
    unsigned short* __restrict__ ash, unsigned short* __restrict__ asl,
    unsigned short* __restrict__ xmh, unsigned short* __restrict__ xml,
    unsigned short* __restrict__ wvh, unsigned short* __restrict__ wvl,
    unsigned short* __restrict__ wch, unsigned short* __restrict__ wcl,
    unsigned short* __restrict__ woh, unsigned short* __restrict__ wol,
    float* __restrict__ bcat) {
  const int bid = blockIdx.x, t = threadIdx.x;
  if (bid < 4096) {
    const int gid = bid * 256 + t;
    const int row = gid >> 6, c4 = (gid & 63) * 4;
    const float* xr = x + (size_t)row * 768 + c4;
    float4 a0 = *(const float4*)xr;
    float4 a1 = *(const float4*)(xr + 256);
    float4 a2 = *(const float4*)(xr + 512);
    float s[4] = {a0.x + a1.x + a2.x, a0.y + a1.y + a2.y,
                  a0.z + a1.z + a2.z, a0.w + a1.w + a2.w};
    float m[4] = {a1.x, a1.y, a1.z, a1.w};
    bf16x4 shv, slv, mhv, mlv;
#pragma unroll
    for (int j = 0; j < 4; ++j) {
      unsigned short h = f2bf(s[j]);
      shv[j] = (short)h; slv[j] = (short)f2bf(s[j] - bf2f(h));
      unsigned short h2 = f2bf(m[j]);
      mhv[j] = (short)h2; mlv[j] = (short)f2bf(m[j] - bf2f(h2));
    }
    const size_t o = (size_t)row * 256 + c4;
    *(bf16x4*)(ash + o) = shv;  *(bf16x4*)(asl + o) = slv;
    *(bf16x4*)(xmh + o) = mhv;  *(bf16x4*)(xml + o) = mlv;
  } else {
    const int n = bid - 4096;
    {
      float v = W_v[(size_t)t * 256 + n];
      unsigned short h = f2bf(v);
      wvh[n * 256 + t] = h; wvl[n * 256 + t] = f2bf(v - bf2f(h));
    }
    {
      float v = W_o[(size_t)t * 256 + n];
      unsigned short h = f2bf(v);
      woh[n * 256 + t] = h; wol[n * 256 + t] = f2bf(v - bf2f(h));
    }
    if (n < 216) {
      float v = (n < 144) ? W_off[(size_t)t * 144 + n] : W_attn[(size_t)t * 72 + (n - 144)];
      unsigned short h = f2bf(v);
      wch[n * 256 + t] = h; wcl[n * 256 + t] = f2bf(v - bf2f(h));
    }
    if (n == 0 && t < 216) bcat[t] = (t < 144) ? b_off[t] : b_attn[t - 144];
  }
}

// ---------------- fused GEMM: valsum (y=0..3) + proj (y=4..7) --------------
// BM=64, BN=64, BK=64; 4 waves (2x2), each wave 32x32. Reg-prefetch pipeline.
__global__ __launch_bounds__(256, 4) void mgemm01(
    const unsigned short* __restrict__ Ahi, const unsigned short* __restrict__ Alo,
    const unsigned short* __restrict__ Xmh, const unsigned short* __restrict__ Xml,
    const unsigned short* __restrict__ Wvh, const unsigned short* __restrict__ Wvl,
    const unsigned short* __restrict__ Wch, const unsigned short* __restrict__ Wcl,
    const float* __restrict__ b_v, const float* __restrict__ bcat,
    float* __restrict__ valsum, float* __restrict__ proj) {
  __shared__ unsigned short Ah[64][64], Al[64][64], Bh[64][64], Bl[64][64];
  const int mode1 = blockIdx.y >= 4;
  const int n0 = (blockIdx.y & 3) * 64;
  const int m0 = blockIdx.x * 64;
  const int tid = threadIdx.x, wid = tid >> 6, lane = tid & 63;
  const int am = (wid >> 1) * 32, bn = (wid & 1) * 32;
  const int fr = lane & 15, kg = lane >> 4;
  const unsigned short* Ahs = mode1 ? Xmh : Ahi;
  const unsigned short* Als = mode1 ? Xml : Alo;
  const unsigned short* Bhs = mode1 ? Wch : Wvh;
  const unsigned short* Bls = mode1 ? Wcl : Wvl;

  const int r0s = tid >> 3, c0s = tid & 7;   // staging slot 0 (rows 0..31)
  const int r1s = r0s + 32;                  // staging slot 1 (rows 32..63)
  const int d0s = r0s * 64 + ((c0s ^ (r0s & 7)) * 8);
  const int d1s = r1s * 64 + ((c0s ^ (r1s & 7)) * 8);

  f32x4 acc[2][2];
#pragma unroll
  for (int i = 0; i < 2; ++i)
#pragma unroll
    for (int j = 0; j < 2; ++j) acc[i][j] = (f32x4)(0.f);

  bf16x8 pah[2], pal[2], pbh[2], pbl[2];

#define LOADT01(k0)                                                          \
  {                                                                          \
    size_t a0 = (size_t)(m0 + r0s) * 256 + (k0) + c0s * 8;                   \
    size_t a1 = (size_t)(m0 + r1s) * 256 + (k0) + c0s * 8;                   \
    pah[0] = *(const bf16x8*)(Ahs + a0); pal[0] = *(const bf16x8*)(Als + a0);\
    pah[1] = *(const bf16x8*)(Ahs + a1); pal[1] = *(const bf16x8*)(Als + a1);\
    int nr0 = n0 + r0s, nr1 = n0 + r1s;                                      \
    size_t b0 = (size_t)nr0 * 256 + (k0) + c0s * 8;                          \
    size_t b1 = (size_t)nr1 * 256 + (k0) + c0s * 8;                          \
    if (!mode1 || nr0 < 216) {                                               \
      pbh[0] = *(const bf16x8*)(Bhs + b0); pbl[0] = *(const bf16x8*)(Bls + b0);\
    } else { pbh[0] = (bf16x8)(short)0; pbl[0] = (bf16x8)(short)0; }         \
    if (!mode1 || nr1 < 216) {                                               \
      pbh[1] = *(const bf16x8*)(Bhs + b1); pbl[1] = *(const bf16x8*)(Bls + b1);\
    } else { pbh[1] = (bf16x8)(short)0; pbl[1] = (bf16x8)(short)0; }         \
  }

#define WRITET()                                                             \
  {                                                                          \
    *(bf16x8*)(&Ah[0][0] + d0s) = pah[0]; *(bf16x8*)(&Al[0][0] + d0s) = pal[0];\
    *(bf16x8*)(&Ah[0][0] + d1s) = pah[1]; *(bf16x8*)(&Al[0][0] + d1s) = pal[1];\
    *(bf16x8*)(&Bh[0][0] + d0s) = pbh[0]; *(bf16x8*)(&Bl[0][0] + d0s) = pbl[0];\
    *(bf16x8*)(&Bh[0][0] + d1s) = pbh[1]; *(bf16x8*)(&Bl[0][0] + d1s) = pbl[1];\
  }

#define COMPUTET()                                                           \
  _Pragma("unroll")                                                          \
  for (int ks = 0; ks < 2; ++ks) {                                           \
    const int kc = ks * 4 + kg;                                              \
    bf16x8 ah[2], al[2], bh[2], bl[2];                                       \
    _Pragma("unroll")                                                        \
    for (int mi = 0; mi < 2; ++mi) {                                         \
      int m = am + mi * 16 + fr;                                             \
      int o = m * 64 + ((kc ^ (m & 7)) * 8);                                 \
      ah[mi] = *(const bf16x8*)(&Ah[0][0] + o);                              \
      al[mi] = *(const bf16x8*)(&Al[0][0] + o);                              \
    }                                                                        \
    _Pragma("unroll")                                                        \
    for (int ni = 0; ni < 2; ++ni) {                                         \
      int nn = bn + ni * 16 + fr;                                            \
      int o = nn * 64 + ((kc ^ (nn & 7)) * 8);                               \
      bh[ni] = *(const bf16x8*)(&Bh[0][0] + o);                              \
      bl[ni] = *(const bf16x8*)(&Bl[0][0] + o);                              \
    }                                                                        \
    _Pragma("unroll")                                                        \
    for (int mi = 0; mi < 2; ++mi)                                           \
      _Pragma("unroll")                                                      \
      for (int ni = 0; ni < 2; ++ni) {                                       \
        acc[mi][ni] = __builtin_amdgcn_mfma_f32_16x16x32_bf16(ah[mi], bh[ni], acc[mi][ni], 0, 0, 0);\
        acc[mi][ni] = __builtin_amdgcn_mfma_f32_16x16x32_bf16(ah[mi], bl[ni], acc[mi][ni], 0, 0, 0);\
        acc[mi][ni] = __builtin_amdgcn_mfma_f32_16x16x32_bf16(al[mi], bh[ni], acc[mi][ni], 0, 0, 0);\
      }                                                                      \
  }

  LOADT01(0);
  WRITET();
  __syncthreads();
#pragma unroll
  for (int t = 0; t < 4; ++t) {
    if (t < 3) LOADT01((t + 1) * 64);
    COMPUTET();
    __syncthreads();
    if (t < 3) { WRITET(); __syncthreads(); }
  }

  const int ro = kg * 4;
#pragma unroll
  for (int mi = 0; mi < 2; ++mi)
#pragma unroll
    for (int ni = 0; ni < 2; ++ni) {
      int col = n0 + bn + ni * 16 + fr;
      if (mode1 && col >= 216) continue;
      int rowb = m0 + am + mi * 16 + ro;
      float bv = mode1 ? bcat[col] : b_v[col] * 3.f;
#pragma unroll
      for (int r = 0; r < 4; ++r) {
        int grow = rowb + r;
        float v = acc[mi][ni][r] + bv;
        if (mode1) {
          proj[(size_t)grow * 216 + col] = v;
        } else {
          int b = grow >> 12, nn2 = grow & 4095;
          int h = col >> 5, d = col & 31;
          valsum[(((size_t)(b * NH_ + h) << 12) + nn2) * DH_ + d] = v;
        }
      }
    }
#undef LOADT01
#undef WRITET
#undef COMPUTET
}

// ---------------- O-GEMM: out = inter(f32) @ W_o + b_o ---------------------
__global__ __launch_bounds__(256, 4) void mgemm2(
    const float* __restrict__ Af, 
    const unsigned short* __restrict__ Bhs, const unsigned short* __restrict__ Bls,
    const float* __restrict__ bias, float* __restrict__ Cout) {
  __shared__ unsigned short Ah[64][64], Al[64][64], Bh[64][64], Bl[64][64];
  const int n0 = blockIdx.y * 64;
  const int m0 = blockIdx.x * 64;
  const int tid = threadIdx.x, wid = tid >> 6, lane = tid & 63;
  const int am = (wid >> 1) * 32, bn = (wid & 1) * 32;
  const int fr = lane & 15, kg = lane >> 4;

  const int r0s = tid >> 3, c0s = tid & 7;
  const int r1s = r0s + 32;
  const int d0s = r0s * 64 + ((c0s ^ (r0s & 7)) * 8);
  const int d1s = r1s * 64 + ((c0s ^ (r1s & 7)) * 8);

  f32x4 acc[2][2];
#pragma unroll
  for (int i = 0; i < 2; ++i)
#pragma unroll
    for (int j = 0; j < 2; ++j) acc[i][j] = (f32x4)(0.f);

  float4 pf[2][2];
  bf16x8 pbh[2], pbl[2];

#define LOADT2(k0)                                                           \
  {                                                                          \
    const float* s0 = Af + (size_t)(m0 + r0s) * 256 + (k0) + c0s * 8;        \
    const float* s1 = Af + (size_t)(m0 + r1s) * 256 + (k0) + c0s * 8;        \
    pf[0][0] = *(const float4*)s0; pf[0][1] = *(const float4*)(s0 + 4);      \
    pf[1][0] = *(const float4*)s1; pf[1][1] = *(const float4*)(s1 + 4);      \
    size_t b0 = (size_t)(n0 + r0s) * 256 + (k0) + c0s * 8;                   \
    size_t b1 = (size_t)(n0 + r1s) * 256 + (k0) + c0s * 8;                   \
    pbh[0] = *(const bf16x8*)(Bhs + b0); pbl[0] = *(const bf16x8*)(Bls + b0);\
    pbh[1] = *(const bf16x8*)(Bhs + b1); pbl[1] = *(const bf16x8*)(Bls + b1);\
  }

#define WRITET2()                                                            \
  {                                                                          \
    bf16x8 hv, lv;                                                           \
    split8(pf[0][0], pf[0][1], hv, lv);                                      \
    *(bf16x8*)(&Ah[0][0] + d0s) = hv; *(bf16x8*)(&Al[0][0] + d0s) = lv;      \
    split8(pf[1][0], pf[1][1], hv, lv);                                      \
    *(bf16x8*)(&Ah[0][0] + d1s) = hv; *(bf16x8*)(&Al[0][0] + d1s) = lv;      \
    *(bf16x8*)(&Bh[0][0] + d0s) = pbh[0]; *(bf16x8*)(&Bl[0][0] + d0s) = pbl[0];\
    *(bf16x8*)(&Bh[0][0] + d1s) = pbh[1]; *(bf16x8*)(&Bl[0][0] + d1s) = pbl[1];\
  }

#define COMPUTET2()                                                          \
  _Pragma("unroll")                                                          \
  for (int ks = 0; ks < 2; ++ks) {                                           \
    const int kc = ks * 4 + kg;                                              \
    bf16x8 ah[2], al[2], bh[2], bl[2];                                       \
    _Pragma("unroll")                                                        \
    for (int mi = 0; mi < 2; ++mi) {                                         \
      int m = am + mi * 16 + fr;                                             \
      int o = m * 64 + ((kc ^ (m & 7)) * 8);                                 \
      ah[mi] = *(const bf16x8*)(&Ah[0][0] + o);                              \
      al[mi] = *(const bf16x8*)(&Al[0][0] + o);                              \
    }                                                                        \
    _Pragma("unroll")                                                        \
    for (int ni = 0; ni < 2; ++ni) {                                         \
      int nn = bn + ni * 16 + fr;                                            \
      int o = nn * 64 + ((kc ^ (nn & 7)) * 8);                               \
      bh[ni] = *(const bf16x8*)(&Bh[0][0] + o);                              \
      bl[ni] = *(const bf16x8*)(&Bl[0][0] + o);                              \
    }                                                                        \
    _Pragma("unroll")                                                        \
    for (int mi = 0; mi < 2; ++mi)                                           \
      _Pragma("unroll")                                                      \
      for (int ni = 0; ni < 2; ++ni) {                                       \
        acc[mi][ni] = __builtin_amdgcn_mfma_f32_16x16x32_bf16(ah[mi], bh[ni], acc[mi][ni], 0, 0, 0);\
        acc[mi][ni] = __builtin_amdgcn_mfma_f32_16x16x32_bf16(ah[mi], bl[ni], acc[mi][ni], 0, 0, 0);\
        acc[mi][ni] = __builtin_amdgcn_mfma_f32_16x16x32_bf16(al[mi], bh[ni], acc[mi][ni], 0, 0, 0);\
      }                                                                      \
  }

  LOADT2(0);
  WRITET2();
  __syncthreads();
#pragma unroll
  for (int t = 0; t < 4; ++t) {
    if (t < 3) LOADT2((t + 1) * 64);
    COMPUTET2();
    __syncthreads();
    if (t < 3) { WRITET2(); __syncthreads(); }
  }

  const int ro = kg * 4;
#pragma unroll
  for (int mi = 0; mi < 2; ++mi)
#pragma unroll
    for (int ni = 0; ni < 2; ++ni) {
      int col = n0 + bn + ni * 16 + fr;
      int rowb = m0 + am + mi * 16 + ro;
      float bv = bias[col];
#pragma unroll
      for (int r = 0; r < 4; ++r)
        Cout[(size_t)(rowb + r) * 256 + col] = acc[mi][ni][r] + bv;
    }
#undef LOADT2
#undef WRITET2
#undef COMPUTET2
}

// ---------------- sampler: 4 pixels / block, folded weights, f32 out -------
struct IW { int idx; float w; };

__global__ __launch_bounds__(256) void sample4(const float* __restrict__ valsum,
                                               const float* __restrict__ proj,
                                               float* __restrict__ inter) {
  const int bid = blockIdx.x;                 // 4096 blocks
  const int wv = threadIdx.x >> 6;
  const int lane = threadIdx.x & 63;
  const int row = ((bid & 7) << 11) + ((bid >> 3) << 2) + wv;  // XCD-chunked
  const int b = row >> 12, n = row & 4095;

  __shared__ IW cwi[4][72][4];
  __shared__ float sap[4][76];

  const float* pr = proj + (size_t)row * 216;
  if (lane < 8) {
    const float* pa = pr + 144 + lane * 9;
    float lg[9], mx = -1e30f;
#pragma unroll
    for (int p = 0; p < 9; ++p) { lg[p] = pa[p]; mx = fmaxf(mx, lg[p]); }
    float s = 0.f;
#pragma unroll
    for (int p = 0; p < 9; ++p) { lg[p] = __expf(lg[p] - mx); s += lg[p]; }
    float inv = 1.f / s;
#pragma unroll
    for (int p = 0; p < 9; ++p) sap[wv][lane * 9 + p] = lg[p] * inv;
  }
  __syncthreads();
  for (int e = lane; e < 72; e += 64) {
    float ox = pr[e * 2], oy = pr[e * 2 + 1];
    float gx = (float)(n & 63) + ox * 31.5f;
    float gy = (float)(n >> 6) + oy * 31.5f;
    float fx0 = floorf(gx), fy0 = floorf(gy);
    float wx1 = gx - fx0, wy1 = gy - fy0;
    float wx0 = 1.f - wx1, wy0 = 1.f - wy1;
    int x0 = (int)fx0, y0 = (int)fy0, x1 = x0 + 1, y1 = y0 + 1;
    bool vx0 = (x0 >= 0) & (x0 < 64), vx1 = (x1 >= 0) & (x1 < 64);
    bool vy0 = (y0 >= 0) & (y0 < 64), vy1 = (y1 >= 0) & (y1 < 64);
    int x0c = min(max(x0, 0), 63), x1c = min(max(x1, 0), 63);
    int y0c = min(max(y0, 0), 63), y1c = min(max(y1, 0), 63);
    const float a = sap[wv][e];
    cwi[wv][e][0] = IW{(y0c * 64 + x0c) * DH_, (vx0 & vy0) ? wx0 * wy0 * a : 0.f};
    cwi[wv][e][1] = IW{(y0c * 64 + x1c) * DH_, (vx1 & vy0) ? wx1 * wy0 * a : 0.f};
    cwi[wv][e][2] = IW{(y1c * 64 + x0c) * DH_, (vx0 & vy1) ? wx0 * wy1 * a : 0.f};
    cwi[wv][e][3] = IW{(y1c * 64 + x1c) * DH_, (vx1 & vy1) ? wx1 * wy1 * a : 0.f};
  }
  __syncthreads();

  const int h = lane >> 3, d4 = (lane & 7) * 4;
  const float* vb = valsum + (((size_t)(b * NH_ + h)) << 12) * DH_ + d4;
  float ax = 0.f, ay = 0.f, az = 0.f, aw = 0.f;
#pragma unroll
  for (int pb = 0; pb < 9; pb += 3) {
    float4 v[12]; float w[12];
#pragma unroll
    for (int q = 0; q < 3; ++q) {
      const int hp = h * 9 + pb + q;
#pragma unroll
      for (int c = 0; c < 4; ++c) {
        IW e = cwi[wv][hp][c];
        v[q * 4 + c] = *(const float4*)(vb + e.idx);
        w[q * 4 + c] = e.w;
      }
    }
#pragma unroll
    for (int j = 0; j < 12; ++j) {
      ax += w[j] * v[j].x; ay += w[j] * v[j].y;
      az += w[j] * v[j].z; aw += w[j] * v[j].w;
    }
  }
  *(float4*)(inter + (size_t)row * 256 + h * DH_ + d4) = make_float4(ax, ay, az, aw);
}

extern "C" void kernel_launch(void* const* d_in, const int* in_sizes, int n_in,
                              void* d_out, int out_size, void* d_ws, size_t ws_size,
                              hipStream_t stream) {
  const float* x      = (const float*)d_in[0];
  const float* W_off  = (const float*)d_in[1];
  const float* b_off  = (const float*)d_in[2];
  const float* W_attn = (const float*)d_in[3];
  const float* b_attn = (const float*)d_in[4];
  const float* W_v    = (const float*)d_in[5];
  const float* b_v    = (const float*)d_in[6];
  const float* W_o    = (const float*)d_in[7];
  const float* b_o    = (const float*)d_in[8];
  float* out = (float*)d_out;

  // ---- workspace layout
  float* valsum = (float*)d_ws;                         // 16384*256 f32
  float* proj   = valsum + (size_t)MM_ * 256;           // 16384*216 f32
  float* bcat   = proj + (size_t)MM_ * 216;             // 256 f32
  unsigned short* ash = (unsigned short*)(bcat + 256);  // 16384*256 bf16
  unsigned short* asl = ash + (size_t)MM_ * 256;
  unsigned short* xmh = asl + (size_t)MM_ * 256;        // 16384*256 bf16
  unsigned short* xml = xmh + (size_t)MM_ * 256;
  unsigned short* wvh = xml + (size_t)MM_ * 256;        // 256*256
  unsigned short* wvl = wvh + 65536;
  unsigned short* wch = wvl + 65536;                    // 216*256
  unsigned short* wcl = wch + 55296;
  unsigned short* woh = wcl + 55296;                    // 256*256
  unsigned short* wol = woh + 65536;
  // inter (f32, 16 MB) aliases ash+asl (dead after mgemm01)
  float* inter = (float*)ash;

  prep<<<dim3(4352), dim3(256), 0, stream>>>(x, W_off, W_attn, W_v, W_o, b_off, b_attn,
                                             ash, asl, xmh, xml,
                                             wvh, wvl, wch, wcl, woh, wol, bcat);
  mgemm01<<<dim3(256, 8), dim3(256), 0, stream>>>(ash, asl, xmh, xml, wvh, wvl, wch, wcl,
                                                  b_v, bcat, valsum, proj);
  sample4<<<dim3(4096), dim3(256), 0, stream>>>(valsum, proj, inter);
  mgemm2<<<dim3(256, 4), dim3(256), 0, stream>>>(inter, woh, wol, b_o, out);
}

// Round 7
// 162.249 us; speedup vs baseline: 1.9556x; 1.0247x over previous
//
#include <hip/hip_runtime.h>
#include <hip/hip_bf16.h>
#include <hip/hip_fp16.h>

// DeformableTemporalAttention — MI355X (gfx950)
// B=4, N=4096 (64x64), T=3, D=256, H=8, P=9, dh=32
//
// Pipeline (4 dispatches):
//  1. prep    : asum = sum_t x -> bf16 hi/lo;  xmid -> bf16 hi/lo;
//               weights transposed+split to bf16 hi/lo [n][k]; bcat packed
//  2. mgemm01 : fused  valsum(fp16) = asum @ W_v + 3*b_v   (blocks y=0..3)
//                      proj(f32)    = xmid @ [W_off|W_attn] + bcat (y=4..7)
//               BM=BN=BK=64, 32KB LDS, reg-prefetch pipeline, 3-pass bf16 split
//  3. sample4 : 4 pixels / 256-thr block, attn folded into corner weights,
//               fp16 gathers (halved L2 traffic) -> inter bf16 hi/lo
//  4. mgemm2  : out = inter @ W_o + b_o

#define NH_ 8
#define DH_ 32
#define MM_ 16384   // B*N

typedef __attribute__((ext_vector_type(8))) short bf16x8;
typedef __attribute__((ext_vector_type(4))) short bf16x4;
typedef __attribute__((ext_vector_type(4))) float f32x4;

static __device__ __forceinline__ unsigned short f2bf(float f) {
  unsigned int u = __float_as_uint(f);
  u = (u + 0x7fff + ((u >> 16) & 1)) >> 16;   // RN-even
  return (unsigned short)u;
}
static __device__ __forceinline__ float bf2f(unsigned short h) {
  return __uint_as_float(((unsigned int)h) << 16);
}

// ---------------- prep: A-side splits + weight transpose/splits ------------
__global__ __launch_bounds__(256) void prep(
    const float* __restrict__ x,
    const float* __restrict__ W_off, const float* __restrict__ W_attn,
    const float* __restrict__ W_v, const float* __restrict__ W_o,
    const float* __restrict__ b_off, const float* __restrict__ b_attn,
    unsigned short* __restrict__ ash, unsigned short* __restrict__ asl,
    unsigned short* __restrict__ xmh, unsigned short* __restrict__ xml,
    unsigned short* __restrict__ wvh, unsigned short* __restrict__ wvl,
    unsigned short* __restrict__ wch, unsigned short* __restrict__ wcl,
    unsigned short* __restrict__ woh, unsigned short* __restrict__ wol,
    float* __restrict__ bcat) {
  const int bid = blockIdx.x, t = threadIdx.x;
  if (bid < 4096) {
    const int gid = bid * 256 + t;
    const int row = gid >> 6, c4 = (gid & 63) * 4;
    const float* xr = x + (size_t)row * 768 + c4;
    float4 a0 = *(const float4*)xr;
    float4 a1 = *(const float4*)(xr + 256);
    float4 a2 = *(const float4*)(xr + 512);
    float s[4] = {a0.x + a1.x + a2.x, a0.y + a1.y + a2.y,
                  a0.z + a1.z + a2.z, a0.w + a1.w + a2.w};
    float m[4] = {a1.x, a1.y, a1.z, a1.w};
    bf16x4 shv, slv, mhv, mlv;
#pragma unroll
    for (int j = 0; j < 4; ++j) {
      unsigned short h = f2bf(s[j]);
      shv[j] = (short)h; slv[j] = (short)f2bf(s[j] - bf2f(h));
      unsigned short h2 = f2bf(m[j]);
      mhv[j] = (short)h2; mlv[j] = (short)f2bf(m[j] - bf2f(h2));
    }
    const size_t o = (size_t)row * 256 + c4;
    *(bf16x4*)(ash + o) = shv;  *(bf16x4*)(asl + o) = slv;
    *(bf16x4*)(xmh + o) = mhv;  *(bf16x4*)(xml + o) = mlv;
  } else {
    const int n = bid - 4096;
    {
      float v = W_v[(size_t)t * 256 + n];
      unsigned short h = f2bf(v);
      wvh[n * 256 + t] = h; wvl[n * 256 + t] = f2bf(v - bf2f(h));
    }
    {
      float v = W_o[(size_t)t * 256 + n];
      unsigned short h = f2bf(v);
      woh[n * 256 + t] = h; wol[n * 256 + t] = f2bf(v - bf2f(h));
    }
    if (n < 216) {
      float v = (n < 144) ? W_off[(size_t)t * 144 + n] : W_attn[(size_t)t * 72 + (n - 144)];
      unsigned short h = f2bf(v);
      wch[n * 256 + t] = h; wcl[n * 256 + t] = f2bf(v - bf2f(h));
    }
    if (n == 0 && t < 216) bcat[t] = (t < 144) ? b_off[t] : b_attn[t - 144];
  }
}

// ---------------- fused GEMM: valsum fp16 (y=0..3) + proj (y=4..7) ---------
// BM=64, BN=64, BK=64; 4 waves (2x2), each wave 32x32. Reg-prefetch pipeline.
__global__ __launch_bounds__(256, 4) void mgemm01(
    const unsigned short* __restrict__ Ahi, const unsigned short* __restrict__ Alo,
    const unsigned short* __restrict__ Xmh, const unsigned short* __restrict__ Xml,
    const unsigned short* __restrict__ Wvh, const unsigned short* __restrict__ Wvl,
    const unsigned short* __restrict__ Wch, const unsigned short* __restrict__ Wcl,
    const float* __restrict__ b_v, const float* __restrict__ bcat,
    __half* __restrict__ valsum, float* __restrict__ proj) {
  __shared__ unsigned short Ah[64][64], Al[64][64], Bh[64][64], Bl[64][64];
  const int mode1 = blockIdx.y >= 4;
  const int n0 = (blockIdx.y & 3) * 64;
  const int m0 = blockIdx.x * 64;
  const int tid = threadIdx.x, wid = tid >> 6, lane = tid & 63;
  const int am = (wid >> 1) * 32, bn = (wid & 1) * 32;
  const int fr = lane & 15, kg = lane >> 4;
  const unsigned short* Ahs = mode1 ? Xmh : Ahi;
  const unsigned short* Als = mode1 ? Xml : Alo;
  const unsigned short* Bhs = mode1 ? Wch : Wvh;
  const unsigned short* Bls = mode1 ? Wcl : Wvl;

  const int r0s = tid >> 3, c0s = tid & 7;   // staging slot 0 (rows 0..31)
  const int r1s = r0s + 32;                  // staging slot 1 (rows 32..63)
  const int d0s = r0s * 64 + ((c0s ^ (r0s & 7)) * 8);
  const int d1s = r1s * 64 + ((c0s ^ (r1s & 7)) * 8);

  f32x4 acc[2][2];
#pragma unroll
  for (int i = 0; i < 2; ++i)
#pragma unroll
    for (int j = 0; j < 2; ++j) acc[i][j] = (f32x4)(0.f);

  bf16x8 pah[2], pal[2], pbh[2], pbl[2];

#define LOADT01(k0)                                                          \
  {                                                                          \
    size_t a0 = (size_t)(m0 + r0s) * 256 + (k0) + c0s * 8;                   \
    size_t a1 = (size_t)(m0 + r1s) * 256 + (k0) + c0s * 8;                   \
    pah[0] = *(const bf16x8*)(Ahs + a0); pal[0] = *(const bf16x8*)(Als + a0);\
    pah[1] = *(const bf16x8*)(Ahs + a1); pal[1] = *(const bf16x8*)(Als + a1);\
    int nr0 = n0 + r0s, nr1 = n0 + r1s;                                      \
    size_t b0 = (size_t)nr0 * 256 + (k0) + c0s * 8;                          \
    size_t b1 = (size_t)nr1 * 256 + (k0) + c0s * 8;                          \
    if (!mode1 || nr0 < 216) {                                               \
      pbh[0] = *(const bf16x8*)(Bhs + b0); pbl[0] = *(const bf16x8*)(Bls + b0);\
    } else { pbh[0] = (bf16x8)(short)0; pbl[0] = (bf16x8)(short)0; }         \
    if (!mode1 || nr1 < 216) {                                               \
      pbh[1] = *(const bf16x8*)(Bhs + b1); pbl[1] = *(const bf16x8*)(Bls + b1);\
    } else { pbh[1] = (bf16x8)(short)0; pbl[1] = (bf16x8)(short)0; }         \
  }

#define WRITET()                                                             \
  {                                                                          \
    *(bf16x8*)(&Ah[0][0] + d0s) = pah[0]; *(bf16x8*)(&Al[0][0] + d0s) = pal[0];\
    *(bf16x8*)(&Ah[0][0] + d1s) = pah[1]; *(bf16x8*)(&Al[0][0] + d1s) = pal[1];\
    *(bf16x8*)(&Bh[0][0] + d0s) = pbh[0]; *(bf16x8*)(&Bl[0][0] + d0s) = pbl[0];\
    *(bf16x8*)(&Bh[0][0] + d1s) = pbh[1]; *(bf16x8*)(&Bl[0][0] + d1s) = pbl[1];\
  }

#define COMPUTET()                                                           \
  _Pragma("unroll")                                                          \
  for (int ks = 0; ks < 2; ++ks) {                                           \
    const int kc = ks * 4 + kg;                                              \
    bf16x8 ah[2], al[2], bh[2], bl[2];                                       \
    _Pragma("unroll")                                                        \
    for (int mi = 0; mi < 2; ++mi) {                                         \
      int m = am + mi * 16 + fr;                                             \
      int o = m * 64 + ((kc ^ (m & 7)) * 8);                                 \
      ah[mi] = *(const bf16x8*)(&Ah[0][0] + o);                              \
      al[mi] = *(const bf16x8*)(&Al[0][0] + o);                              \
    }                                                                        \
    _Pragma("unroll")                                                        \
    for (int ni = 0; ni < 2; ++ni) {                                         \
      int nn = bn + ni * 16 + fr;                                            \
      int o = nn * 64 + ((kc ^ (nn & 7)) * 8);                               \
      bh[ni] = *(const bf16x8*)(&Bh[0][0] + o);                              \
      bl[ni] = *(const bf16x8*)(&Bl[0][0] + o);                              \
    }                                                                        \
    _Pragma("unroll")                                                        \
    for (int mi = 0; mi < 2; ++mi)                                           \
      _Pragma("unroll")                                                      \
      for (int ni = 0; ni < 2; ++ni) {                                       \
        acc[mi][ni] = __builtin_amdgcn_mfma_f32_16x16x32_bf16(ah[mi], bh[ni], acc[mi][ni], 0, 0, 0);\
        acc[mi][ni] = __builtin_amdgcn_mfma_f32_16x16x32_bf16(ah[mi], bl[ni], acc[mi][ni], 0, 0, 0);\
        acc[mi][ni] = __builtin_amdgcn_mfma_f32_16x16x32_bf16(al[mi], bh[ni], acc[mi][ni], 0, 0, 0);\
      }                                                                      \
  }

  LOADT01(0);
  WRITET();
  __syncthreads();
#pragma unroll
  for (int t = 0; t < 4; ++t) {
    if (t < 3) LOADT01((t + 1) * 64);
    COMPUTET();
    __syncthreads();
    if (t < 3) { WRITET(); __syncthreads(); }
  }

  const int ro = kg * 4;
#pragma unroll
  for (int mi = 0; mi < 2; ++mi)
#pragma unroll
    for (int ni = 0; ni < 2; ++ni) {
      int col = n0 + bn + ni * 16 + fr;
      if (mode1 && col >= 216) continue;
      int rowb = m0 + am + mi * 16 + ro;
      float bv = mode1 ? bcat[col] : b_v[col] * 3.f;
#pragma unroll
      for (int r = 0; r < 4; ++r) {
        int grow = rowb + r;
        float v = acc[mi][ni][r] + bv;
        if (mode1) {
          proj[(size_t)grow * 216 + col] = v;
        } else {
          int b = grow >> 12, nn2 = grow & 4095;
          int h = col >> 5, d = col & 31;
          valsum[(((size_t)(b * NH_ + h) << 12) + nn2) * DH_ + d] = __float2half_rn(v);
        }
      }
    }
#undef LOADT01
#undef WRITET
#undef COMPUTET
}

// ---------------- O-GEMM: out = inter(bf16 hi/lo) @ W_o + b_o --------------
__global__ __launch_bounds__(256, 4) void mgemm2(
    const unsigned short* __restrict__ Ahi, const unsigned short* __restrict__ Alo,
    const unsigned short* __restrict__ Bhs, const unsigned short* __restrict__ Bls,
    const float* __restrict__ bias, float* __restrict__ Cout) {
  __shared__ unsigned short Ah[64][64], Al[64][64], Bh[64][64], Bl[64][64];
  const int n0 = blockIdx.y * 64;
  const int m0 = blockIdx.x * 64;
  const int tid = threadIdx.x, wid = tid >> 6, lane = tid & 63;
  const int am = (wid >> 1) * 32, bn = (wid & 1) * 32;
  const int fr = lane & 15, kg = lane >> 4;

  const int r0s = tid >> 3, c0s = tid & 7;
  const int r1s = r0s + 32;
  const int d0s = r0s * 64 + ((c0s ^ (r0s & 7)) * 8);
  const int d1s = r1s * 64 + ((c0s ^ (r1s & 7)) * 8);

  f32x4 acc[2][2];
#pragma unroll
  for (int i = 0; i < 2; ++i)
#pragma unroll
    for (int j = 0; j < 2; ++j) acc[i][j] = (f32x4)(0.f);

  bf16x8 pah[2], pal[2], pbh[2], pbl[2];

#define LOADT2(k0)                                                           \
  {                                                                          \
    size_t a0 = (size_t)(m0 + r0s) * 256 + (k0) + c0s * 8;                   \
    size_t a1 = (size_t)(m0 + r1s) * 256 + (k0) + c0s * 8;                   \
    pah[0] = *(const bf16x8*)(Ahi + a0); pal[0] = *(const bf16x8*)(Alo + a0);\
    pah[1] = *(const bf16x8*)(Ahi + a1); pal[1] = *(const bf16x8*)(Alo + a1);\
    size_t b0 = (size_t)(n0 + r0s) * 256 + (k0) + c0s * 8;                   \
    size_t b1 = (size_t)(n0 + r1s) * 256 + (k0) + c0s * 8;                   \
    pbh[0] = *(const bf16x8*)(Bhs + b0); pbl[0] = *(const bf16x8*)(Bls + b0);\
    pbh[1] = *(const bf16x8*)(Bhs + b1); pbl[1] = *(const bf16x8*)(Bls + b1);\
  }

#define WRITET2()                                                            \
  {                                                                          \
    *(bf16x8*)(&Ah[0][0] + d0s) = pah[0]; *(bf16x8*)(&Al[0][0] + d0s) = pal[0];\
    *(bf16x8*)(&Ah[0][0] + d1s) = pah[1]; *(bf16x8*)(&Al[0][0] + d1s) = pal[1];\
    *(bf16x8*)(&Bh[0][0] + d0s) = pbh[0]; *(bf16x8*)(&Bl[0][0] + d0s) = pbl[0];\
    *(bf16x8*)(&Bh[0][0] + d1s) = pbh[1]; *(bf16x8*)(&Bl[0][0] + d1s) = pbl[1];\
  }

#define COMPUTET2()                                                          \
  _Pragma("unroll")                                                          \
  for (int ks = 0; ks < 2; ++ks) {                                           \
    const int kc = ks * 4 + kg;                                              \
    bf16x8 ah[2], al[2], bh[2], bl[2];                                       \
    _Pragma("unroll")                                                        \
    for (int mi = 0; mi < 2; ++mi) {                                         \
      int m = am + mi * 16 + fr;                                             \
      int o = m * 64 + ((kc ^ (m & 7)) * 8);                                 \
      ah[mi] = *(const bf16x8*)(&Ah[0][0] + o);                              \
      al[mi] = *(const bf16x8*)(&Al[0][0] + o);                              \
    }                                                                        \
    _Pragma("unroll")                                                        \
    for (int ni = 0; ni < 2; ++ni) {                                         \
      int nn = bn + ni * 16 + fr;                                            \
      int o = nn * 64 + ((kc ^ (nn & 7)) * 8);                               \
      bh[ni] = *(const bf16x8*)(&Bh[0][0] + o);                              \
      bl[ni] = *(const bf16x8*)(&Bl[0][0] + o);                              \
    }                                                                        \
    _Pragma("unroll")                                                        \
    for (int mi = 0; mi < 2; ++mi)                                           \
      _Pragma("unroll")                                                      \
      for (int ni = 0; ni < 2; ++ni) {                                       \
        acc[mi][ni] = __builtin_amdgcn_mfma_f32_16x16x32_bf16(ah[mi], bh[ni], acc[mi][ni], 0, 0, 0);\
        acc[mi][ni] = __builtin_amdgcn_mfma_f32_16x16x32_bf16(ah[mi], bl[ni], acc[mi][ni], 0, 0, 0);\
        acc[mi][ni] = __builtin_amdgcn_mfma_f32_16x16x32_bf16(al[mi], bh[ni], acc[mi][ni], 0, 0, 0);\
      }                                                                      \
  }

  LOADT2(0);
  WRITET2();
  __syncthreads();
#pragma unroll
  for (int t = 0; t < 4; ++t) {
    if (t < 3) LOADT2((t + 1) * 64);
    COMPUTET2();
    __syncthreads();
    if (t < 3) { WRITET2(); __syncthreads(); }
  }

  const int ro = kg * 4;
#pragma unroll
  for (int mi = 0; mi < 2; ++mi)
#pragma unroll
    for (int ni = 0; ni < 2; ++ni) {
      int col = n0 + bn + ni * 16 + fr;
      int rowb = m0 + am + mi * 16 + ro;
      float bv = bias[col];
#pragma unroll
      for (int r = 0; r < 4; ++r)
        Cout[(size_t)(rowb + r) * 256 + col] = acc[mi][ni][r] + bv;
    }
#undef LOADT2
#undef WRITET2
#undef COMPUTET2
}

// ---------------- sampler: 4 px / block, fp16 gathers, bf16 hi/lo out ------
struct IW { int idx; float w; };

__global__ __launch_bounds__(256) void sample4(const __half* __restrict__ valsum,
                                               const float* __restrict__ proj,
                                               unsigned short* __restrict__ ihi,
                                               unsigned short* __restrict__ ilo) {
  const int bid = blockIdx.x;                 // 4096 blocks
  const int wv = threadIdx.x >> 6;
  const int lane = threadIdx.x & 63;
  const int row = ((bid & 7) << 11) + ((bid >> 3) << 2) + wv;  // XCD-chunked
  const int b = row >> 12, n = row & 4095;

  __shared__ IW cwi[4][72][4];
  __shared__ float sap[4][76];

  const float* pr = proj + (size_t)row * 216;
  if (lane < 8) {
    const float* pa = pr + 144 + lane * 9;
    float lg[9], mx = -1e30f;
#pragma unroll
    for (int p = 0; p < 9; ++p) { lg[p] = pa[p]; mx = fmaxf(mx, lg[p]); }
    float s = 0.f;
#pragma unroll
    for (int p = 0; p < 9; ++p) { lg[p] = __expf(lg[p] - mx); s += lg[p]; }
    float inv = 1.f / s;
#pragma unroll
    for (int p = 0; p < 9; ++p) sap[wv][lane * 9 + p] = lg[p] * inv;
  }
  __syncthreads();
  for (int e = lane; e < 72; e += 64) {
    float ox = pr[e * 2], oy = pr[e * 2 + 1];
    float gx = (float)(n & 63) + ox * 31.5f;
    float gy = (float)(n >> 6) + oy * 31.5f;
    float fx0 = floorf(gx), fy0 = floorf(gy);
    float wx1 = gx - fx0, wy1 = gy - fy0;
    float wx0 = 1.f - wx1, wy0 = 1.f - wy1;
    int x0 = (int)fx0, y0 = (int)fy0, x1 = x0 + 1, y1 = y0 + 1;
    bool vx0 = (x0 >= 0) & (x0 < 64), vx1 = (x1 >= 0) & (x1 < 64);
    bool vy0 = (y0 >= 0) & (y0 < 64), vy1 = (y1 >= 0) & (y1 < 64);
    int x0c = min(max(x0, 0), 63), x1c = min(max(x1, 0), 63);
    int y0c = min(max(y0, 0), 63), y1c = min(max(y1, 0), 63);
    const float a = sap[wv][e];
    cwi[wv][e][0] = IW{(y0c * 64 + x0c) * DH_, (vx0 & vy0) ? wx0 * wy0 * a : 0.f};
    cwi[wv][e][1] = IW{(y0c * 64 + x1c) * DH_, (vx1 & vy0) ? wx1 * wy0 * a : 0.f};
    cwi[wv][e][2] = IW{(y1c * 64 + x0c) * DH_, (vx0 & vy1) ? wx0 * wy1 * a : 0.f};
    cwi[wv][e][3] = IW{(y1c * 64 + x1c) * DH_, (vx1 & vy1) ? wx1 * wy1 * a : 0.f};
  }
  __syncthreads();

  const int h = lane >> 3, d4 = (lane & 7) * 4;
  const __half* vb = valsum + (((size_t)(b * NH_ + h)) << 12) * DH_ + d4;
  float ax = 0.f, ay = 0.f, az = 0.f, aw = 0.f;
#pragma unroll
  for (int pb = 0; pb < 9; pb += 3) {
    float2 v[24]; float w[12];
#pragma unroll
    for (int q = 0; q < 3; ++q) {
      const int hp = h * 9 + pb + q;
#pragma unroll
      for (int c = 0; c < 4; ++c) {
        IW e = cwi[wv][hp][c];
        const __half2* p = (const __half2*)(vb + e.idx);
        v[(q * 4 + c) * 2 + 0] = __half22float2(p[0]);
        v[(q * 4 + c) * 2 + 1] = __half22float2(p[1]);
        w[q * 4 + c] = e.w;
      }
    }
#pragma unroll
    for (int j = 0; j < 12; ++j) {
      ax += w[j] * v[j * 2].x;     ay += w[j] * v[j * 2].y;
      az += w[j] * v[j * 2 + 1].x; aw += w[j] * v[j * 2 + 1].y;
    }
  }
  float av[4] = {ax, ay, az, aw};
  bf16x4 hv, lv;
#pragma unroll
  for (int j = 0; j < 4; ++j) {
    unsigned short hh = f2bf(av[j]);
    hv[j] = (short)hh;
    lv[j] = (short)f2bf(av[j] - bf2f(hh));
  }
  const size_t o = (size_t)row * 256 + lane * 4;   // == row*256 + h*32 + d4
  *(bf16x4*)(ihi + o) = hv;
  *(bf16x4*)(ilo + o) = lv;
}

extern "C" void kernel_launch(void* const* d_in, const int* in_sizes, int n_in,
                              void* d_out, int out_size, void* d_ws, size_t ws_size,
                              hipStream_t stream) {
  const float* x      = (const float*)d_in[0];
  const float* W_off  = (const float*)d_in[1];
  const float* b_off  = (const float*)d_in[2];
  const float* W_attn = (const float*)d_in[3];
  const float* b_attn = (const float*)d_in[4];
  const float* W_v    = (const float*)d_in[5];
  const float* b_v    = (const float*)d_in[6];
  const float* W_o    = (const float*)d_in[7];
  const float* b_o    = (const float*)d_in[8];
  float* out = (float*)d_out;

  // ---- workspace layout
  __half* valsum = (__half*)d_ws;                       // 16384*256 fp16 (8 MB)
  float* proj    = (float*)(valsum + (size_t)MM_ * 256);// 16384*216 f32
  float* bcat    = proj + (size_t)MM_ * 216;            // 256 f32
  unsigned short* ash = (unsigned short*)(bcat + 256);  // 16384*256 bf16
  unsigned short* asl = ash + (size_t)MM_ * 256;
  unsigned short* xmh = asl + (size_t)MM_ * 256;        // 16384*256 bf16
  unsigned short* xml = xmh + (size_t)MM_ * 256;
  unsigned short* wvh = xml + (size_t)MM_ * 256;        // 256*256
  unsigned short* wvl = wvh + 65536;
  unsigned short* wch = wvl + 65536;                    // 216*256
  unsigned short* wcl = wch + 55296;
  unsigned short* woh = wcl + 55296;                    // 256*256
  unsigned short* wol = woh + 65536;
  // inter hi/lo alias ash/asl (dead after mgemm01)
  unsigned short* ihi = ash;
  unsigned short* ilo = asl;

  prep<<<dim3(4352), dim3(256), 0, stream>>>(x, W_off, W_attn, W_v, W_o, b_off, b_attn,
                                             ash, asl, xmh, xml,
                                             wvh, wvl, wch, wcl, woh, wol, bcat);
  mgemm01<<<dim3(256, 8), dim3(256), 0, stream>>>(ash, asl, xmh, xml, wvh, wvl, wch, wcl,
                                                  b_v, bcat, valsum, proj);
  sample4<<<dim3(4096), dim3(256), 0, stream>>>(valsum, proj, ihi, ilo);
  mgemm2<<<dim3(256, 4), dim3(256), 0, stream>>>(ihi, ilo, woh, wol, b_o, out);
}